// Round 3
// baseline (1270.570 us; speedup 1.0000x reference)
//
#include <hip/hip_runtime.h>
#include <hip/hip_bf16.h>
#include <cstddef>

// Problem constants
// x:(64,197,768) tokens:(1,64,9,768) qkv_w:(2304,768) proj_w:(768,768)
// proj_b:(768) prompts:(2,10,8,12,64). NUM_HEADS=12, hd=64, T_TASK=0.

typedef __attribute__((ext_vector_type(8))) short    bf16x8;   // MFMA A/B frag (8 bf16)
typedef __attribute__((ext_vector_type(8))) unsigned short ushort8;
typedef __attribute__((ext_vector_type(4))) float    f32x4;    // MFMA C/D frag

__device__ __forceinline__ unsigned short f2bf_rne(float f) {
    unsigned int u = __float_as_uint(f);
    u += 0x7fff + ((u >> 16) & 1);           // round-to-nearest-even
    return (unsigned short)(u >> 16);
}
__device__ __forceinline__ float bf2f(unsigned short h) {
    return __uint_as_float(((unsigned int)h) << 16);
}

// ---------------------------------------------------------------------------
// bf16 hi/lo split MFMA GEMM: C(M,N) = A(M,K) @ Bw(N,K)^T (+bias)
// fp32-class accuracy via hi*hi + hi*lo + lo*hi (error ~2^-16).
// 128x128 tile, 4 waves (2x2), 64x64 per wave, BK=32, m97-style 2-barrier loop.
// N % 128 == 0, K % 32 == 0; M guarded.
// ---------------------------------------------------------------------------
#define LDK 40   // padded LDS row stride in ushorts (80 B = 20 banks -> 2-way max)

__global__ __launch_bounds__(256)
void gemm_mfma_kernel(const float* __restrict__ A, const float* __restrict__ Bw,
                      const float* __restrict__ bias, float* __restrict__ C,
                      int M, int N, int K)
{
    __shared__ unsigned short Ah[128][LDK], Al[128][LDK];
    __shared__ unsigned short Bh[128][LDK], Bl[128][LDK];

    const int tid = threadIdx.x;
    const int m0 = blockIdx.y * 128;
    const int n0 = blockIdx.x * 128;
    const int wave = tid >> 6, lane = tid & 63;
    const int wr = wave >> 1, wc = wave & 1;      // 2x2 wave grid
    const int l15 = lane & 15, kg = lane >> 4;    // frag col/row + k-group

    f32x4 zero4 = {0.f, 0.f, 0.f, 0.f};
    f32x4 acc[4][4];
#pragma unroll
    for (int i = 0; i < 4; ++i)
#pragma unroll
        for (int j = 0; j < 4; ++j) acc[i][j] = zero4;

    // staging role: thread covers (row = tid>>1, 16-float half = tid&1)
    const int srow  = tid >> 1;
    const int shalf = tid & 1;
    const int sgm   = m0 + srow;
    const bool arow_ok = (sgm < M);
    const float* aptr = A  + (size_t)sgm * K + shalf * 16;
    const float* bptr = Bw + (size_t)(n0 + srow) * K + shalf * 16;

    for (int k0 = 0; k0 < K; k0 += 32) {
        // issue global loads early (latency hides under barrier arrival)
        f32x4 av[4], bv[4];
#pragma unroll
        for (int i = 0; i < 4; ++i) {
            av[i] = arow_ok ? *(const f32x4*)(aptr + k0 + i * 4) : zero4;
            bv[i] = *(const f32x4*)(bptr + k0 + i * 4);
        }
        __syncthreads();   // all waves done reading previous tile

        // convert fp32 -> bf16 hi/lo, write LDS (2x ds_write_b128 per tile)
        ushort8 h, l;
#pragma unroll
        for (int half = 0; half < 2; ++half) {
#pragma unroll
            for (int i = 0; i < 8; ++i) {
                float v = av[half * 2 + (i >> 2)][i & 3];
                unsigned short hh = f2bf_rne(v);
                h[i] = hh;
                l[i] = f2bf_rne(v - bf2f(hh));
            }
            *(ushort8*)&Ah[srow][shalf * 16 + half * 8] = h;
            *(ushort8*)&Al[srow][shalf * 16 + half * 8] = l;
        }
#pragma unroll
        for (int half = 0; half < 2; ++half) {
#pragma unroll
            for (int i = 0; i < 8; ++i) {
                float v = bv[half * 2 + (i >> 2)][i & 3];
                unsigned short hh = f2bf_rne(v);
                h[i] = hh;
                l[i] = f2bf_rne(v - bf2f(hh));
            }
            *(ushort8*)&Bh[srow][shalf * 16 + half * 8] = h;
            *(ushort8*)&Bl[srow][shalf * 16 + half * 8] = l;
        }
        __syncthreads();   // tile visible

        // fragment loads: A row = lane&15 (+16*f), k = (lane>>4)*8 .. +7
        bf16x8 afh[4], afl[4], bfh[4], bfl[4];
#pragma unroll
        for (int f = 0; f < 4; ++f) {
            const int ar = wr * 64 + f * 16 + l15;
            afh[f] = *(const bf16x8*)&Ah[ar][kg * 8];
            afl[f] = *(const bf16x8*)&Al[ar][kg * 8];
            const int br = wc * 64 + f * 16 + l15;
            bfh[f] = *(const bf16x8*)&Bh[br][kg * 8];
            bfl[f] = *(const bf16x8*)&Bl[br][kg * 8];
        }
#pragma unroll
        for (int fm = 0; fm < 4; ++fm)
#pragma unroll
            for (int fn = 0; fn < 4; ++fn) {
                acc[fm][fn] = __builtin_amdgcn_mfma_f32_16x16x32_bf16(
                    afh[fm], bfh[fn], acc[fm][fn], 0, 0, 0);
                acc[fm][fn] = __builtin_amdgcn_mfma_f32_16x16x32_bf16(
                    afh[fm], bfl[fn], acc[fm][fn], 0, 0, 0);
                acc[fm][fn] = __builtin_amdgcn_mfma_f32_16x16x32_bf16(
                    afl[fm], bfh[fn], acc[fm][fn], 0, 0, 0);
            }
    }

    // epilogue: C/D layout col = lane&15, row = (lane>>4)*4 + reg  [m89/m91]
#pragma unroll
    for (int fm = 0; fm < 4; ++fm)
#pragma unroll
        for (int fn = 0; fn < 4; ++fn) {
            const int col = n0 + wc * 64 + fn * 16 + l15;
            const float bvv = bias ? bias[col] : 0.f;
#pragma unroll
            for (int j = 0; j < 4; ++j) {
                const int row = m0 + wr * 64 + fm * 16 + kg * 4 + j;
                if (row < M) C[(size_t)row * N + col] = acc[fm][fn][j] + bvv;
            }
        }
}

// ---------------------------------------------------------------------------
// Task gather: per batch b — selector cross-attention pooling over patches.
// Writes task_x (9x768 per b) and tokens_out selector rows (s=1..8).
// ---------------------------------------------------------------------------
__global__ __launch_bounds__(256)
void task_gather_kernel(const float* __restrict__ x, const float* __restrict__ tokens,
                        float* __restrict__ task_x, float* __restrict__ out_tok)
{
    const int b = blockIdx.x;
    const int tid = threadIdx.x;
    __shared__ float sel[8][772];   // padded: bank-spread across s
    __shared__ float g[8][200];

    // load selectors (tokens rows 1..8), also copy straight to tokens_out
    for (int l = tid; l < 8 * 192; l += 256) {
        int s = l / 192, c4 = l % 192;
        float4 v = *(const float4*)&tokens[((size_t)b * 9 + 1 + s) * 768 + c4 * 4];
        sel[s][c4 * 4 + 0] = v.x; sel[s][c4 * 4 + 1] = v.y;
        sel[s][c4 * 4 + 2] = v.z; sel[s][c4 * 4 + 3] = v.w;
        *(float4*)&out_tok[((size_t)b * 9 + 1 + s) * 768 + c4 * 4] = v;
    }
    __syncthreads();

    const float token_scale = 0.03608439182435161f;  // 768^-0.5
    for (int idx = tid; idx < 197 * 8; idx += 256) {
        int n = idx >> 3, s = idx & 7;
        const float* xr = &x[((size_t)b * 197 + n) * 768];
        float acc = 0.f;
        for (int c4 = 0; c4 < 192; ++c4) {
            float4 xv = *(const float4*)&xr[c4 * 4];
            acc = fmaf(xv.x, sel[s][c4 * 4 + 0], acc);
            acc = fmaf(xv.y, sel[s][c4 * 4 + 1], acc);
            acc = fmaf(xv.z, sel[s][c4 * 4 + 2], acc);
            acc = fmaf(xv.w, sel[s][c4 * 4 + 3], acc);
        }
        g[s][n] = acc * token_scale;
    }
    __syncthreads();

    // softmax over n for each of 8 selector rows (wave per row)
    const int w = tid >> 6, lane = tid & 63;
    for (int s = w; s < 8; s += 4) {
        float vals[4];
        float m = -1e30f;
#pragma unroll
        for (int t = 0; t < 4; ++t) {
            int n = lane + 64 * t;
            vals[t] = (n < 197) ? g[s][n] : -1e30f;
            m = fmaxf(m, vals[t]);
        }
#pragma unroll
        for (int off = 32; off >= 1; off >>= 1) m = fmaxf(m, __shfl_xor(m, off, 64));
        float sum = 0.f;
#pragma unroll
        for (int t = 0; t < 4; ++t) {
            int n = lane + 64 * t;
            if (n < 197) { vals[t] = __expf(vals[t] - m); sum += vals[t]; }
        }
#pragma unroll
        for (int off = 32; off >= 1; off >>= 1) sum += __shfl_xor(sum, off, 64);
        float inv = 1.f / sum;
#pragma unroll
        for (int t = 0; t < 4; ++t) {
            int n = lane + 64 * t;
            if (n < 197) g[s][n] = vals[t] * inv;
        }
    }
    __syncthreads();

    // patches: task_x rows 1..8 = g @ x[b];  row 0 = cls token
    if (tid < 192) {
        float4 acc8[8];
#pragma unroll
        for (int s = 0; s < 8; ++s) acc8[s] = make_float4(0.f, 0.f, 0.f, 0.f);
        for (int n = 0; n < 197; ++n) {
            float4 xv = *(const float4*)&x[((size_t)b * 197 + n) * 768 + tid * 4];
#pragma unroll
            for (int s = 0; s < 8; ++s) {
                float gw = g[s][n];
                acc8[s].x = fmaf(gw, xv.x, acc8[s].x);
                acc8[s].y = fmaf(gw, xv.y, acc8[s].y);
                acc8[s].z = fmaf(gw, xv.z, acc8[s].z);
                acc8[s].w = fmaf(gw, xv.w, acc8[s].w);
            }
        }
#pragma unroll
        for (int s = 0; s < 8; ++s)
            *(float4*)&task_x[((size_t)b * 9 + 1 + s) * 768 + tid * 4] = acc8[s];
        float4 cls = *(const float4*)&tokens[((size_t)b * 9) * 768 + tid * 4];
        *(float4*)&task_x[((size_t)b * 9) * 768 + tid * 4] = cls;
    }
}

// ---------------------------------------------------------------------------
// Main attention, per (head, batch): Q/K/V staged in LDS (K XOR-swizzled),
// one wave per query row, shuffles for softmax + P broadcast.
// ---------------------------------------------------------------------------
__global__ __launch_bounds__(512)
void attn_main_kernel(const float* __restrict__ qkv2, float* __restrict__ attn_o)
{
    const int h = blockIdx.x;
    const int b = blockIdx.y;
    const int tid = threadIdx.x;
    const int w = tid >> 6;
    const int lane = tid & 63;

    __shared__ float Qs[197][64];
    __shared__ float Ks[197][64];   // float4-slot XOR swizzle per row
    __shared__ float Vs[200][64];   // 3 pad rows (zeroed) so unguarded PV reads are safe

    const size_t base = (size_t)b * 197 * 2304 + (size_t)h * 64;
    for (int l = tid; l < 197 * 16; l += 512) {
        int n = l >> 4, d4 = l & 15;
        const float* p = &qkv2[base + (size_t)n * 2304 + d4 * 4];
        float4 q4 = *(const float4*)(p);
        float4 k4 = *(const float4*)(p + 768);
        float4 v4 = *(const float4*)(p + 1536);
        *(float4*)&Qs[n][d4 * 4] = q4;
        *(float4*)&Ks[n][(d4 ^ (n & 15)) * 4] = k4;
        *(float4*)&Vs[n][d4 * 4] = v4;
    }
    // zero the 3 pad rows of Vs (PV reads them unguarded with p=0)
    if (tid < 48) {
        int n = 197 + tid / 16, d4 = tid & 15;
        *(float4*)&Vs[n][d4 * 4] = make_float4(0.f, 0.f, 0.f, 0.f);
    }
    __syncthreads();

    const int d4 = lane & 15, jo = lane >> 4;

    for (int n = w; n < 197; n += 8) {
        float4 qreg[16];
#pragma unroll
        for (int q = 0; q < 16; ++q) qreg[q] = *(const float4*)&Qs[n][q * 4];

        float s[4];
        float m = -1e30f;
#pragma unroll
        for (int t = 0; t < 4; ++t) {
            int j = lane + 64 * t;
            float a = -1e30f;
            if (j < 197) {
                float acc = 0.f;
                int jx = j & 15;
#pragma unroll
                for (int q = 0; q < 16; ++q) {
                    float4 k4 = *(const float4*)&Ks[j][(q ^ jx) * 4];
                    acc = fmaf(qreg[q].x, k4.x, acc);
                    acc = fmaf(qreg[q].y, k4.y, acc);
                    acc = fmaf(qreg[q].z, k4.z, acc);
                    acc = fmaf(qreg[q].w, k4.w, acc);
                }
                a = acc * 0.125f;
            }
            s[t] = a;
            m = fmaxf(m, a);
        }
#pragma unroll
        for (int off = 32; off >= 1; off >>= 1) m = fmaxf(m, __shfl_xor(m, off, 64));
        float sum = 0.f;
#pragma unroll
        for (int t = 0; t < 4; ++t) {
            int j = lane + 64 * t;
            float e = 0.f;
            if (j < 197) { e = __expf(s[t] - m); sum += e; }
            s[t] = e;
        }
#pragma unroll
        for (int off = 32; off >= 1; off >>= 1) sum += __shfl_xor(sum, off, 64);
        const float inv = 1.f / sum;

        // PV: lane (jo,d4) accumulates dims d4*4..+3 over keys j ≡ jo (mod 4).
        // Keys 197..199 have p==0 and zeroed Vs rows -> no guard needed.
        float4 acc = make_float4(0.f, 0.f, 0.f, 0.f);
#pragma unroll
        for (int t = 0; t < 4; ++t) {
            const int kmax = (t < 3) ? 16 : 2;
#pragma unroll 4
            for (int k2 = 0; k2 < kmax; ++k2) {
                int j = t * 64 + k2 * 4 + jo;
                float p = __shfl(s[t], j & 63, 64);
                float4 v4 = *(const float4*)&Vs[j][d4 * 4];
                acc.x = fmaf(p, v4.x, acc.x);
                acc.y = fmaf(p, v4.y, acc.y);
                acc.z = fmaf(p, v4.z, acc.z);
                acc.w = fmaf(p, v4.w, acc.w);
            }
        }
#pragma unroll
        for (int off = 16; off <= 32; off <<= 1) {
            acc.x += __shfl_xor(acc.x, off, 64);
            acc.y += __shfl_xor(acc.y, off, 64);
            acc.z += __shfl_xor(acc.z, off, 64);
            acc.w += __shfl_xor(acc.w, off, 64);
        }
        if (jo == 0) {
            float4 o = make_float4(acc.x * inv, acc.y * inv, acc.z * inv, acc.w * inv);
            *(float4*)&attn_o[((size_t)(b * 197 + n)) * 768 + h * 64 + d4 * 4] = o;
        }
    }
}

// ---------------------------------------------------------------------------
// Task attention per (h, b): only the cls-row query matters for the output.
// Computes q0, K(9), V(9) from task_x, prepends 8 prompt K/V rows, attends.
// ---------------------------------------------------------------------------
__global__ __launch_bounds__(256)
void task_attn_kernel(const float* __restrict__ task_x_g, const float* __restrict__ qkv_w,
                      const float* __restrict__ prompts, float* __restrict__ out0)
{
    const int h = blockIdx.x, b = blockIdx.y;
    const int tid = threadIdx.x;
    __shared__ float txs[9][772];
    __shared__ float kk_s[17][64];
    __shared__ float vv_s[17][64];
    __shared__ float q0s[64];

    for (int l = tid; l < 9 * 192; l += 256) {
        int s = l / 192, c4 = l % 192;
        float4 v = *(const float4*)&task_x_g[((size_t)b * 9 + s) * 768 + c4 * 4];
        txs[s][c4 * 4 + 0] = v.x; txs[s][c4 * 4 + 1] = v.y;
        txs[s][c4 * 4 + 2] = v.z; txs[s][c4 * 4 + 3] = v.w;
    }
    // prompts: (2,10,8,12,64), nt=T_TASK=0. keys 0..7 / values 0..7
    for (int l = tid; l < 8 * 64; l += 256) {
        int p = l >> 6, d = l & 63;
        kk_s[p][d] = prompts[(size_t)(p * 12 + h) * 64 + d];
        vv_s[p][d] = prompts[(size_t)61440 + (size_t)(p * 12 + h) * 64 + d];
    }
    __syncthreads();

    // 1216 dots of length 768: q0 (64), K rows (9*64), V rows (9*64)
    for (int id = tid; id < 1216; id += 256) {
        int kind, s, d;
        if (id < 64) { kind = 0; s = 0; d = id; }
        else if (id < 640) { kind = 1; int t = id - 64; s = t >> 6; d = t & 63; }
        else { kind = 2; int t = id - 640; s = t >> 6; d = t & 63; }
        const int wrow = (kind == 0 ? 0 : (kind == 1 ? 768 : 1536)) + h * 64 + d;
        const float* wp = &qkv_w[(size_t)wrow * 768];
        const float* xr = txs[s];
        float acc = 0.f;
        for (int c4 = 0; c4 < 192; ++c4) {
            float4 wv = *(const float4*)&wp[c4 * 4];
            acc = fmaf(wv.x, xr[c4 * 4 + 0], acc);
            acc = fmaf(wv.y, xr[c4 * 4 + 1], acc);
            acc = fmaf(wv.z, xr[c4 * 4 + 2], acc);
            acc = fmaf(wv.w, xr[c4 * 4 + 3], acc);
        }
        if (kind == 0) q0s[d] = acc;
        else if (kind == 1) kk_s[8 + s][d] = acc;
        else vv_s[8 + s][d] = acc;
    }
    __syncthreads();

    if (tid < 64) {
        const int lane = tid;
        float sc = -1e30f;
        if (lane < 17) {
            float a = 0.f;
#pragma unroll 8
            for (int d = 0; d < 64; ++d) a = fmaf(q0s[d], kk_s[lane][d], a);
            sc = a * 0.125f;
        }
        float m = sc;
#pragma unroll
        for (int off = 32; off >= 1; off >>= 1) m = fmaxf(m, __shfl_xor(m, off, 64));
        float p = (lane < 17) ? __expf(sc - m) : 0.f;
        float sum = p;
#pragma unroll
        for (int off = 32; off >= 1; off >>= 1) sum += __shfl_xor(sum, off, 64);
        float acc = 0.f;
#pragma unroll
        for (int j = 0; j < 17; ++j) {
            float pj = __shfl(p, j, 64);
            acc = fmaf(pj, vv_s[j][lane], acc);
        }
        out0[((size_t)b * 12 + h) * 64 + lane] = acc / sum;
    }
}

// ---------------------------------------------------------------------------
// Task projection of the cls row only -> tokens_out[:, :, 0, :]
// ---------------------------------------------------------------------------
__global__ __launch_bounds__(256)
void task_proj_kernel(const float* __restrict__ out0, const float* __restrict__ proj_w,
                      const float* __restrict__ proj_b, float* __restrict__ out_tok)
{
    const int b = blockIdx.x;
    const int col = blockIdx.y * 256 + threadIdx.x;
    __shared__ float xr[768];
    for (int l = threadIdx.x; l < 768; l += 256) xr[l] = out0[(size_t)b * 768 + l];
    __syncthreads();
    const float* wp = &proj_w[(size_t)col * 768];
    float acc = proj_b[col];
    for (int c4 = 0; c4 < 192; ++c4) {
        float4 wv = *(const float4*)&wp[c4 * 4];
        acc = fmaf(wv.x, xr[c4 * 4 + 0], acc);
        acc = fmaf(wv.y, xr[c4 * 4 + 1], acc);
        acc = fmaf(wv.z, xr[c4 * 4 + 2], acc);
        acc = fmaf(wv.w, xr[c4 * 4 + 3], acc);
    }
    out_tok[((size_t)b * 9) * 768 + col] = acc;
}

// ---------------------------------------------------------------------------
extern "C" void kernel_launch(void* const* d_in, const int* in_sizes, int n_in,
                              void* d_out, int out_size, void* d_ws, size_t ws_size,
                              hipStream_t stream)
{
    const float* x       = (const float*)d_in[0];
    const float* tokens  = (const float*)d_in[1];
    const float* qkv_w   = (const float*)d_in[2];
    const float* proj_w  = (const float*)d_in[3];
    const float* proj_b  = (const float*)d_in[4];
    const float* prompts = (const float*)d_in[5];

    float* xo      = (float*)d_out;                 // 12608*768
    float* out_tok = xo + (size_t)12608 * 768;      // 64*9*768

    float* qkv2   = (float*)d_ws;                        // 12608*2304
    float* attn_o = qkv2 + (size_t)12608 * 2304;         // 12608*768
    float* task_x = attn_o + (size_t)12608 * 768;        // 64*9*768
    float* out0   = task_x + (size_t)64 * 9 * 768;       // 64*768

    task_gather_kernel<<<dim3(64), 256, 0, stream>>>(x, tokens, task_x, out_tok);

    gemm_mfma_kernel<<<dim3(2304 / 128, (12608 + 127) / 128), 256, 0, stream>>>(
        x, qkv_w, nullptr, qkv2, 12608, 2304, 768);

    attn_main_kernel<<<dim3(12, 64), 512, 0, stream>>>(qkv2, attn_o);

    gemm_mfma_kernel<<<dim3(768 / 128, (12608 + 127) / 128), 256, 0, stream>>>(
        attn_o, proj_w, proj_b, xo, 12608, 768, 768);

    task_attn_kernel<<<dim3(12, 64), 256, 0, stream>>>(task_x, qkv_w, prompts, out0);

    task_proj_kernel<<<dim3(64, 3), 256, 0, stream>>>(out0, proj_w, proj_b, out_tok);
}

// Round 7
// 942.287 us; speedup vs baseline: 1.3484x; 1.3484x over previous
//
#include <hip/hip_runtime.h>
#include <hip/hip_bf16.h>
#include <cstddef>

// Problem constants
// x:(64,197,768) tokens:(1,64,9,768) qkv_w:(2304,768) proj_w:(768,768)
// proj_b:(768) prompts:(2,10,8,12,64). NUM_HEADS=12, hd=64, T_TASK=0.

typedef __attribute__((ext_vector_type(8))) short    bf16x8;   // MFMA A/B frag (8 bf16)
typedef __attribute__((ext_vector_type(8))) unsigned short ushort8;
typedef __attribute__((ext_vector_type(4))) unsigned short ushort4v;
typedef __attribute__((ext_vector_type(4))) float    f32x4;    // MFMA C/D frag

__device__ __forceinline__ unsigned short f2bf_rne(float f) {
    unsigned int u = __float_as_uint(f);
    u += 0x7fff + ((u >> 16) & 1);           // round-to-nearest-even
    return (unsigned short)(u >> 16);
}
__device__ __forceinline__ float bf2f(unsigned short h) {
    return __uint_as_float(((unsigned int)h) << 16);
}

// ---------------------------------------------------------------------------
// bf16 hi/lo split MFMA GEMM: C(M,N) = A(M,K) @ Bw(N,K)^T (+bias)
// fp32-class accuracy via hi*hi + hi*lo + lo*hi (error ~2^-16).
// 128x128 tile, 4 waves (2x2), 64x64 per wave, BK=32, m97-style 2-barrier loop.
// N % 128 == 0, K % 32 == 0; M guarded.  [VALIDATED r3: passed, absmax 9.8e-4]
// ---------------------------------------------------------------------------
#define LDK 40   // padded LDS row stride in ushorts (80 B = 20 banks -> 2-way max)

__global__ __launch_bounds__(256)
void gemm_mfma_kernel(const float* __restrict__ A, const float* __restrict__ Bw,
                      const float* __restrict__ bias, float* __restrict__ C,
                      int M, int N, int K)
{
    __shared__ unsigned short Ah[128][LDK], Al[128][LDK];
    __shared__ unsigned short Bh[128][LDK], Bl[128][LDK];

    const int tid = threadIdx.x;
    const int m0 = blockIdx.y * 128;
    const int n0 = blockIdx.x * 128;
    const int wave = tid >> 6, lane = tid & 63;
    const int wr = wave >> 1, wc = wave & 1;      // 2x2 wave grid
    const int l15 = lane & 15, kg = lane >> 4;    // frag col/row + k-group

    f32x4 zero4 = {0.f, 0.f, 0.f, 0.f};
    f32x4 acc[4][4];
#pragma unroll
    for (int i = 0; i < 4; ++i)
#pragma unroll
        for (int j = 0; j < 4; ++j) acc[i][j] = zero4;

    // staging role: thread covers (row = tid>>1, 16-float half = tid&1)
    const int srow  = tid >> 1;
    const int shalf = tid & 1;
    const int sgm   = m0 + srow;
    const bool arow_ok = (sgm < M);
    const float* aptr = A  + (size_t)sgm * K + shalf * 16;
    const float* bptr = Bw + (size_t)(n0 + srow) * K + shalf * 16;

    for (int k0 = 0; k0 < K; k0 += 32) {
        // issue global loads early (latency hides under barrier arrival)
        f32x4 av[4], bv[4];
#pragma unroll
        for (int i = 0; i < 4; ++i) {
            av[i] = arow_ok ? *(const f32x4*)(aptr + k0 + i * 4) : zero4;
            bv[i] = *(const f32x4*)(bptr + k0 + i * 4);
        }
        __syncthreads();   // all waves done reading previous tile

        // convert fp32 -> bf16 hi/lo, write LDS (2x ds_write_b128 per tile)
        ushort8 h, l;
#pragma unroll
        for (int half = 0; half < 2; ++half) {
#pragma unroll
            for (int i = 0; i < 8; ++i) {
                float v = av[half * 2 + (i >> 2)][i & 3];
                unsigned short hh = f2bf_rne(v);
                h[i] = hh;
                l[i] = f2bf_rne(v - bf2f(hh));
            }
            *(ushort8*)&Ah[srow][shalf * 16 + half * 8] = h;
            *(ushort8*)&Al[srow][shalf * 16 + half * 8] = l;
        }
#pragma unroll
        for (int half = 0; half < 2; ++half) {
#pragma unroll
            for (int i = 0; i < 8; ++i) {
                float v = bv[half * 2 + (i >> 2)][i & 3];
                unsigned short hh = f2bf_rne(v);
                h[i] = hh;
                l[i] = f2bf_rne(v - bf2f(hh));
            }
            *(ushort8*)&Bh[srow][shalf * 16 + half * 8] = h;
            *(ushort8*)&Bl[srow][shalf * 16 + half * 8] = l;
        }
        __syncthreads();   // tile visible

        // fragment loads: A row = lane&15 (+16*f), k = (lane>>4)*8 .. +7
        bf16x8 afh[4], afl[4], bfh[4], bfl[4];
#pragma unroll
        for (int f = 0; f < 4; ++f) {
            const int ar = wr * 64 + f * 16 + l15;
            afh[f] = *(const bf16x8*)&Ah[ar][kg * 8];
            afl[f] = *(const bf16x8*)&Al[ar][kg * 8];
            const int br = wc * 64 + f * 16 + l15;
            bfh[f] = *(const bf16x8*)&Bh[br][kg * 8];
            bfl[f] = *(const bf16x8*)&Bl[br][kg * 8];
        }
#pragma unroll
        for (int fm = 0; fm < 4; ++fm)
#pragma unroll
            for (int fn = 0; fn < 4; ++fn) {
                acc[fm][fn] = __builtin_amdgcn_mfma_f32_16x16x32_bf16(
                    afh[fm], bfh[fn], acc[fm][fn], 0, 0, 0);
                acc[fm][fn] = __builtin_amdgcn_mfma_f32_16x16x32_bf16(
                    afh[fm], bfl[fn], acc[fm][fn], 0, 0, 0);
                acc[fm][fn] = __builtin_amdgcn_mfma_f32_16x16x32_bf16(
                    afl[fm], bfh[fn], acc[fm][fn], 0, 0, 0);
            }
    }

    // epilogue: C/D layout col = lane&15, row = (lane>>4)*4 + reg  [m89/m91]
#pragma unroll
    for (int fm = 0; fm < 4; ++fm)
#pragma unroll
        for (int fn = 0; fn < 4; ++fn) {
            const int col = n0 + wc * 64 + fn * 16 + l15;
            const float bvv = bias ? bias[col] : 0.f;
#pragma unroll
            for (int j = 0; j < 4; ++j) {
                const int row = m0 + wr * 64 + fm * 16 + kg * 4 + j;
                if (row < M) C[(size_t)row * N + col] = acc[fm][fn][j] + bvv;
            }
        }
}

// ---------------------------------------------------------------------------
// Task gather: per batch b — selector cross-attention pooling over patches.
// ---------------------------------------------------------------------------
__global__ __launch_bounds__(256)
void task_gather_kernel(const float* __restrict__ x, const float* __restrict__ tokens,
                        float* __restrict__ task_x, float* __restrict__ out_tok)
{
    const int b = blockIdx.x;
    const int tid = threadIdx.x;
    __shared__ float sel[8][772];   // padded: bank-spread across s
    __shared__ float g[8][200];

    for (int l = tid; l < 8 * 192; l += 256) {
        int s = l / 192, c4 = l % 192;
        float4 v = *(const float4*)&tokens[((size_t)b * 9 + 1 + s) * 768 + c4 * 4];
        sel[s][c4 * 4 + 0] = v.x; sel[s][c4 * 4 + 1] = v.y;
        sel[s][c4 * 4 + 2] = v.z; sel[s][c4 * 4 + 3] = v.w;
        *(float4*)&out_tok[((size_t)b * 9 + 1 + s) * 768 + c4 * 4] = v;
    }
    __syncthreads();

    const float token_scale = 0.03608439182435161f;  // 768^-0.5
    for (int idx = tid; idx < 197 * 8; idx += 256) {
        int n = idx >> 3, s = idx & 7;
        const float* xr = &x[((size_t)b * 197 + n) * 768];
        float acc = 0.f;
        for (int c4 = 0; c4 < 192; ++c4) {
            float4 xv = *(const float4*)&xr[c4 * 4];
            acc = fmaf(xv.x, sel[s][c4 * 4 + 0], acc);
            acc = fmaf(xv.y, sel[s][c4 * 4 + 1], acc);
            acc = fmaf(xv.z, sel[s][c4 * 4 + 2], acc);
            acc = fmaf(xv.w, sel[s][c4 * 4 + 3], acc);
        }
        g[s][n] = acc * token_scale;
    }
    __syncthreads();

    const int w = tid >> 6, lane = tid & 63;
    for (int s = w; s < 8; s += 4) {
        float vals[4];
        float m = -1e30f;
#pragma unroll
        for (int t = 0; t < 4; ++t) {
            int n = lane + 64 * t;
            vals[t] = (n < 197) ? g[s][n] : -1e30f;
            m = fmaxf(m, vals[t]);
        }
#pragma unroll
        for (int off = 32; off >= 1; off >>= 1) m = fmaxf(m, __shfl_xor(m, off, 64));
        float sum = 0.f;
#pragma unroll
        for (int t = 0; t < 4; ++t) {
            int n = lane + 64 * t;
            if (n < 197) { vals[t] = __expf(vals[t] - m); sum += vals[t]; }
        }
#pragma unroll
        for (int off = 32; off >= 1; off >>= 1) sum += __shfl_xor(sum, off, 64);
        float inv = 1.f / sum;
#pragma unroll
        for (int t = 0; t < 4; ++t) {
            int n = lane + 64 * t;
            if (n < 197) g[s][n] = vals[t] * inv;
        }
    }
    __syncthreads();

    if (tid < 192) {
        float4 acc8[8];
#pragma unroll
        for (int s = 0; s < 8; ++s) acc8[s] = make_float4(0.f, 0.f, 0.f, 0.f);
        for (int n = 0; n < 197; ++n) {
            float4 xv = *(const float4*)&x[((size_t)b * 197 + n) * 768 + tid * 4];
#pragma unroll
            for (int s = 0; s < 8; ++s) {
                float gw = g[s][n];
                acc8[s].x = fmaf(gw, xv.x, acc8[s].x);
                acc8[s].y = fmaf(gw, xv.y, acc8[s].y);
                acc8[s].z = fmaf(gw, xv.z, acc8[s].z);
                acc8[s].w = fmaf(gw, xv.w, acc8[s].w);
            }
        }
#pragma unroll
        for (int s = 0; s < 8; ++s)
            *(float4*)&task_x[((size_t)b * 9 + 1 + s) * 768 + tid * 4] = acc8[s];
        float4 cls = *(const float4*)&tokens[((size_t)b * 9) * 768 + tid * 4];
        *(float4*)&task_x[((size_t)b * 9) * 768 + tid * 4] = cls;
    }
}

// ---------------------------------------------------------------------------
// Main attention via MFMA (hi/lo bf16 split), per (h, b) block, 4 waves.
// S^T = K@Q^T  (C rows = keys, cols = queries), softmax in-register,
// out^T = V^T @ P^T.  No barriers in the main loop (P-LDS is per-wave).
// K LDS: [197][64] bf16, XOR slot-swizzle (16B slot ^= row&7) -> 2-way free.
// Vt LDS: [64][232] (stride 29*16B -> 2-way free). P: [16][208] per wave.
// Total LDS 163328 B (1 block/CU).
// ---------------------------------------------------------------------------
__global__ __launch_bounds__(256)
void attn_mfma_kernel(const float* __restrict__ qkv2, float* __restrict__ attn_o)
{
    __shared__ alignas(16) unsigned short Khi[198][64], Klo[198][64];
    __shared__ alignas(16) unsigned short Vthi[64][232], Vtlo[64][232];
    __shared__ alignas(16) unsigned short Phi[4][16][208], Plo[4][16][208];

    const int h = blockIdx.x, b = blockIdx.y;
    const int tid = threadIdx.x;
    const int wave = tid >> 6, lane = tid & 63;
    const int l15 = lane & 15, kg = lane >> 4;

    const size_t base = (size_t)b * 197 * 2304 + (size_t)h * 64;

    // ---- stage K (hi/lo, swizzled) and V^T (hi/lo) ----
    for (int l = tid; l < 197 * 16; l += 256) {
        int n = l >> 4, d4 = l & 15;
        const float* p = &qkv2[base + (size_t)n * 2304 + d4 * 4];
        float4 k4 = *(const float4*)(p + 768);
        float4 v4 = *(const float4*)(p + 1536);
        float kf[4] = {k4.x, k4.y, k4.z, k4.w};
        float vf[4] = {v4.x, v4.y, v4.z, v4.w};
        // K row n, dims d4*4..+3 -> swizzled 16B slot ((d4>>1) ^ (n&7))
        const int off = (((d4 >> 1) ^ (n & 7)) << 3) + ((d4 & 1) << 2);
        ushort4v kh, kl;
#pragma unroll
        for (int i = 0; i < 4; ++i) {
            unsigned short hh = f2bf_rne(kf[i]);
            kh[i] = hh;
            kl[i] = f2bf_rne(kf[i] - bf2f(hh));
        }
        *(ushort4v*)&Khi[n][off] = kh;
        *(ushort4v*)&Klo[n][off] = kl;
#pragma unroll
        for (int i = 0; i < 4; ++i) {
            unsigned short hh = f2bf_rne(vf[i]);
            Vthi[d4 * 4 + i][n] = hh;
            Vtlo[d4 * 4 + i][n] = f2bf_rne(vf[i] - bf2f(hh));
        }
    }
    // zero Vt key-columns 197..207 (read by PV step 6 with p==0; avoid 0*NaN)
    for (int l = tid; l < 64 * 11; l += 256) {
        int d = l / 11, c = 197 + l % 11;
        Vthi[d][c] = 0;
        Vtlo[d][c] = 0;
    }
    __syncthreads();

    // ---- per-wave query tiles (16 queries each; 13 tiles) ----
    for (int qt = wave; qt < 13; qt += 4) {
        const int n0 = qt * 16;
        const int qrow = (n0 + l15 < 197) ? (n0 + l15) : 196;

        // Q B-frags from global, pre-scaled by hd^-0.5 = 0.125 (exact)
        bf16x8 qh[2], ql[2];
#pragma unroll
        for (int s = 0; s < 2; ++s) {
            const float* qp = &qkv2[base + (size_t)qrow * 2304 + kg * 8 + 32 * s];
            float4 qa = *(const float4*)qp;
            float4 qb = *(const float4*)(qp + 4);
            float qf[8] = {qa.x, qa.y, qa.z, qa.w, qb.x, qb.y, qb.z, qb.w};
#pragma unroll
            for (int i = 0; i < 8; ++i) {
                float v = qf[i] * 0.125f;
                unsigned short hh = f2bf_rne(v);
                qh[s][i] = (short)hh;
                ql[s][i] = (short)f2bf_rne(v - bf2f(hh));
            }
        }

        // S^T = K @ Q^T : 13 key-tiles x 2 K-steps x 3 (hi/lo) MFMA
        f32x4 st[13];
#pragma unroll
        for (int t = 0; t < 13; ++t) st[t] = (f32x4){0.f, 0.f, 0.f, 0.f};
#pragma unroll
        for (int t = 0; t < 13; ++t) {
            const int r = 16 * t + l15;               // key row held by this lane
            const bool ok = (t < 12) || (l15 < 5);    // rows 197+ -> zero frag
#pragma unroll
            for (int s = 0; s < 2; ++s) {
                bf16x8 kh = {0, 0, 0, 0, 0, 0, 0, 0};
                bf16x8 kl = {0, 0, 0, 0, 0, 0, 0, 0};
                if (ok) {
                    const int off = (((kg + 4 * s) ^ (l15 & 7)) << 3);
                    kh = *(const bf16x8*)&Khi[r][off];
                    kl = *(const bf16x8*)&Klo[r][off];
                }
                st[t] = __builtin_amdgcn_mfma_f32_16x16x32_bf16(kh, qh[s], st[t], 0, 0, 0);
                st[t] = __builtin_amdgcn_mfma_f32_16x16x32_bf16(kh, ql[s], st[t], 0, 0, 0);
                st[t] = __builtin_amdgcn_mfma_f32_16x16x32_bf16(kl, qh[s], st[t], 0, 0, 0);
            }
        }

        // softmax over keys for query col l15 (rows = keys 16t+kg*4+j)
        float m = -1e30f;
#pragma unroll
        for (int t = 0; t < 13; ++t)
#pragma unroll
            for (int j = 0; j < 4; ++j) {
                const int key = 16 * t + kg * 4 + j;
                float v = (key < 197) ? st[t][j] : -1e30f;
                st[t][j] = v;
                m = fmaxf(m, v);
            }
        m = fmaxf(m, __shfl_xor(m, 16, 64));
        m = fmaxf(m, __shfl_xor(m, 32, 64));
        float sum = 0.f;
#pragma unroll
        for (int t = 0; t < 13; ++t)
#pragma unroll
            for (int j = 0; j < 4; ++j) {
                float e = __expf(st[t][j] - m);   // masked -> exp(-huge) = 0
                st[t][j] = e;
                sum += e;
            }
        sum += __shfl_xor(sum, 16, 64);
        sum += __shfl_xor(sum, 32, 64);
        const float inv = 1.f / sum;              // applied at epilogue

        // pack P (unnormalized) to per-wave LDS, bf16 hi/lo
#pragma unroll
        for (int t = 0; t < 13; ++t) {
            ushort4v ph, pl;
#pragma unroll
            for (int j = 0; j < 4; ++j) {
                unsigned short hh = f2bf_rne(st[t][j]);
                ph[j] = hh;
                pl[j] = f2bf_rne(st[t][j] - bf2f(hh));
            }
            *(ushort4v*)&Phi[wave][l15][16 * t + kg * 4] = ph;
            *(ushort4v*)&Plo[wave][l15][16 * t + kg * 4] = pl;
        }

        // out^T = V^T @ P^T : 7 K-steps (32 keys) x 4 d-frags x 3 MFMA
        f32x4 ao[4];
#pragma unroll
        for (int fd = 0; fd < 4; ++fd) ao[fd] = (f32x4){0.f, 0.f, 0.f, 0.f};
#pragma unroll
        for (int s = 0; s < 7; ++s) {
            const bool act = (s < 6) || (kg < 2);   // keys 208+ -> zero frags
            bf16x8 ph = {0, 0, 0, 0, 0, 0, 0, 0};
            bf16x8 pl = {0, 0, 0, 0, 0, 0, 0, 0};
            if (act) {
                ph = *(const bf16x8*)&Phi[wave][l15][kg * 8 + 32 * s];
                pl = *(const bf16x8*)&Plo[wave][l15][kg * 8 + 32 * s];
            }
#pragma unroll
            for (int fd = 0; fd < 4; ++fd) {
                bf16x8 vh = {0, 0, 0, 0, 0, 0, 0, 0};
                bf16x8 vl = {0, 0, 0, 0, 0, 0, 0, 0};
                if (act) {
                    vh = *(const bf16x8*)&Vthi[fd * 16 + l15][kg * 8 + 32 * s];
                    vl = *(const bf16x8*)&Vtlo[fd * 16 + l15][kg * 8 + 32 * s];
                }
                ao[fd] = __builtin_amdgcn_mfma_f32_16x16x32_bf16(vh, ph, ao[fd], 0, 0, 0);
                ao[fd] = __builtin_amdgcn_mfma_f32_16x16x32_bf16(vh, pl, ao[fd], 0, 0, 0);
                ao[fd] = __builtin_amdgcn_mfma_f32_16x16x32_bf16(vl, ph, ao[fd], 0, 0, 0);
            }
        }

        // epilogue: out[query n0+l15][d = fd*16 + kg*4 + j] = ao * inv
        if (n0 + l15 < 197) {
            float* op = &attn_o[((size_t)(b * 197 + n0 + l15)) * 768 + h * 64];
#pragma unroll
            for (int fd = 0; fd < 4; ++fd) {
                float4 o = make_float4(ao[fd][0] * inv, ao[fd][1] * inv,
                                       ao[fd][2] * inv, ao[fd][3] * inv);
                *(float4*)(op + fd * 16 + kg * 4) = o;
            }
        }
    }
}

// ---------------------------------------------------------------------------
// Task attention per (h, b): only the cls-row query matters for the output.
// ---------------------------------------------------------------------------
__global__ __launch_bounds__(256)
void task_attn_kernel(const float* __restrict__ task_x_g, const float* __restrict__ qkv_w,
                      const float* __restrict__ prompts, float* __restrict__ out0)
{
    const int h = blockIdx.x, b = blockIdx.y;
    const int tid = threadIdx.x;
    __shared__ float txs[9][772];
    __shared__ float kk_s[17][64];
    __shared__ float vv_s[17][64];
    __shared__ float q0s[64];

    for (int l = tid; l < 9 * 192; l += 256) {
        int s = l / 192, c4 = l % 192;
        float4 v = *(const float4*)&task_x_g[((size_t)b * 9 + s) * 768 + c4 * 4];
        txs[s][c4 * 4 + 0] = v.x; txs[s][c4 * 4 + 1] = v.y;
        txs[s][c4 * 4 + 2] = v.z; txs[s][c4 * 4 + 3] = v.w;
    }
    for (int l = tid; l < 8 * 64; l += 256) {
        int p = l >> 6, d = l & 63;
        kk_s[p][d] = prompts[(size_t)(p * 12 + h) * 64 + d];
        vv_s[p][d] = prompts[(size_t)61440 + (size_t)(p * 12 + h) * 64 + d];
    }
    __syncthreads();

    for (int id = tid; id < 1216; id += 256) {
        int kind, s, d;
        if (id < 64) { kind = 0; s = 0; d = id; }
        else if (id < 640) { kind = 1; int t = id - 64; s = t >> 6; d = t & 63; }
        else { kind = 2; int t = id - 640; s = t >> 6; d = t & 63; }
        const int wrow = (kind == 0 ? 0 : (kind == 1 ? 768 : 1536)) + h * 64 + d;
        const float* wp = &qkv_w[(size_t)wrow * 768];
        const float* xr = txs[s];
        float acc = 0.f;
        for (int c4 = 0; c4 < 192; ++c4) {
            float4 wv = *(const float4*)&wp[c4 * 4];
            acc = fmaf(wv.x, xr[c4 * 4 + 0], acc);
            acc = fmaf(wv.y, xr[c4 * 4 + 1], acc);
            acc = fmaf(wv.z, xr[c4 * 4 + 2], acc);
            acc = fmaf(wv.w, xr[c4 * 4 + 3], acc);
        }
        if (kind == 0) q0s[d] = acc;
        else if (kind == 1) kk_s[8 + s][d] = acc;
        else vv_s[8 + s][d] = acc;
    }
    __syncthreads();

    if (tid < 64) {
        const int lane = tid;
        float sc = -1e30f;
        if (lane < 17) {
            float a = 0.f;
#pragma unroll 8
            for (int d = 0; d < 64; ++d) a = fmaf(q0s[d], kk_s[lane][d], a);
            sc = a * 0.125f;
        }
        float m = sc;
#pragma unroll
        for (int off = 32; off >= 1; off >>= 1) m = fmaxf(m, __shfl_xor(m, off, 64));
        float p = (lane < 17) ? __expf(sc - m) : 0.f;
        float sum = p;
#pragma unroll
        for (int off = 32; off >= 1; off >>= 1) sum += __shfl_xor(sum, off, 64);
        float acc = 0.f;
#pragma unroll
        for (int j = 0; j < 17; ++j) {
            float pj = __shfl(p, j, 64);
            acc = fmaf(pj, vv_s[j][lane], acc);
        }
        out0[((size_t)b * 12 + h) * 64 + lane] = acc / sum;
    }
}

// ---------------------------------------------------------------------------
// Task projection of the cls row only -> tokens_out[:, :, 0, :]
// ---------------------------------------------------------------------------
__global__ __launch_bounds__(256)
void task_proj_kernel(const float* __restrict__ out0, const float* __restrict__ proj_w,
                      const float* __restrict__ proj_b, float* __restrict__ out_tok)
{
    const int b = blockIdx.x;
    const int col = blockIdx.y * 256 + threadIdx.x;
    __shared__ float xr[768];
    for (int l = threadIdx.x; l < 768; l += 256) xr[l] = out0[(size_t)b * 768 + l];
    __syncthreads();
    const float* wp = &proj_w[(size_t)col * 768];
    float acc = proj_b[col];
    for (int c4 = 0; c4 < 192; ++c4) {
        float4 wv = *(const float4*)&wp[c4 * 4];
        acc = fmaf(wv.x, xr[c4 * 4 + 0], acc);
        acc = fmaf(wv.y, xr[c4 * 4 + 1], acc);
        acc = fmaf(wv.z, xr[c4 * 4 + 2], acc);
        acc = fmaf(wv.w, xr[c4 * 4 + 3], acc);
    }
    out_tok[((size_t)b * 9) * 768 + col] = acc;
}

// ---------------------------------------------------------------------------
extern "C" void kernel_launch(void* const* d_in, const int* in_sizes, int n_in,
                              void* d_out, int out_size, void* d_ws, size_t ws_size,
                              hipStream_t stream)
{
    const float* x       = (const float*)d_in[0];
    const float* tokens  = (const float*)d_in[1];
    const float* qkv_w   = (const float*)d_in[2];
    const float* proj_w  = (const float*)d_in[3];
    const float* proj_b  = (const float*)d_in[4];
    const float* prompts = (const float*)d_in[5];

    float* xo      = (float*)d_out;                 // 12608*768
    float* out_tok = xo + (size_t)12608 * 768;      // 64*9*768

    float* qkv2   = (float*)d_ws;                        // 12608*2304
    float* attn_o = qkv2 + (size_t)12608 * 2304;         // 12608*768
    float* task_x = attn_o + (size_t)12608 * 768;        // 64*9*768
    float* out0   = task_x + (size_t)64 * 9 * 768;       // 64*768

    task_gather_kernel<<<dim3(64), 256, 0, stream>>>(x, tokens, task_x, out_tok);

    gemm_mfma_kernel<<<dim3(2304 / 128, (12608 + 127) / 128), 256, 0, stream>>>(
        x, qkv_w, nullptr, qkv2, 12608, 2304, 768);

    attn_mfma_kernel<<<dim3(12, 64), 256, 0, stream>>>(qkv2, attn_o);

    gemm_mfma_kernel<<<dim3(768 / 128, (12608 + 127) / 128), 256, 0, stream>>>(
        attn_o, proj_w, proj_b, xo, 12608, 768, 768);

    task_attn_kernel<<<dim3(12, 64), 256, 0, stream>>>(task_x, qkv_w, prompts, out0);

    task_proj_kernel<<<dim3(64, 3), 256, 0, stream>>>(out0, proj_w, proj_b, out_tok);
}

// Round 9
// 698.675 us; speedup vs baseline: 1.8185x; 1.3487x over previous
//
#include <hip/hip_runtime.h>
#include <hip/hip_bf16.h>
#include <cstddef>

// Problem constants
// x:(64,197,768) tokens:(1,64,9,768) qkv_w:(2304,768) proj_w:(768,768)
// proj_b:(768) prompts:(2,10,8,12,64). NUM_HEADS=12, hd=64, T_TASK=0.

typedef __attribute__((ext_vector_type(8))) short    bf16x8;   // MFMA A/B frag (8 bf16)
typedef __attribute__((ext_vector_type(8))) unsigned short ushort8;
typedef __attribute__((ext_vector_type(4))) unsigned short ushort4v;
typedef __attribute__((ext_vector_type(4))) float    f32x4;    // MFMA C/D frag

__device__ __forceinline__ unsigned short f2bf_rne(float f) {
    unsigned int u = __float_as_uint(f);
    u += 0x7fff + ((u >> 16) & 1);           // round-to-nearest-even
    return (unsigned short)(u >> 16);
}
__device__ __forceinline__ float bf2f(unsigned short h) {
    return __uint_as_float(((unsigned int)h) << 16);
}

// ---------------------------------------------------------------------------
// bf16 hi/lo split MFMA GEMM: C(M,N) = A(M,K) @ Bw(N,K)^T (+bias)
// fp32-class accuracy via hi*hi + hi*lo + lo*hi (error ~2^-16).
// 128x128 tile, 4 waves (2x2), 64x64 per wave, BK=32, m97-style 2-barrier loop.
// N % 128 == 0, K % 32 == 0; M guarded.  [VALIDATED r3: passed, absmax 9.8e-4]
// ---------------------------------------------------------------------------
#define LDK 40   // padded LDS row stride in ushorts (80 B = 20 banks -> 2-way max)

__global__ __launch_bounds__(256)
void gemm_mfma_kernel(const float* __restrict__ A, const float* __restrict__ Bw,
                      const float* __restrict__ bias, float* __restrict__ C,
                      int M, int N, int K)
{
    __shared__ unsigned short Ah[128][LDK], Al[128][LDK];
    __shared__ unsigned short Bh[128][LDK], Bl[128][LDK];

    const int tid = threadIdx.x;
    const int m0 = blockIdx.y * 128;
    const int n0 = blockIdx.x * 128;
    const int wave = tid >> 6, lane = tid & 63;
    const int wr = wave >> 1, wc = wave & 1;      // 2x2 wave grid
    const int l15 = lane & 15, kg = lane >> 4;    // frag col/row + k-group

    f32x4 zero4 = {0.f, 0.f, 0.f, 0.f};
    f32x4 acc[4][4];
#pragma unroll
    for (int i = 0; i < 4; ++i)
#pragma unroll
        for (int j = 0; j < 4; ++j) acc[i][j] = zero4;

    // staging role: thread covers (row = tid>>1, 16-float half = tid&1)
    const int srow  = tid >> 1;
    const int shalf = tid & 1;
    const int sgm   = m0 + srow;
    const bool arow_ok = (sgm < M);
    const float* aptr = A  + (size_t)sgm * K + shalf * 16;
    const float* bptr = Bw + (size_t)(n0 + srow) * K + shalf * 16;

    for (int k0 = 0; k0 < K; k0 += 32) {
        // issue global loads early (latency hides under barrier arrival)
        f32x4 av[4], bv[4];
#pragma unroll
        for (int i = 0; i < 4; ++i) {
            av[i] = arow_ok ? *(const f32x4*)(aptr + k0 + i * 4) : zero4;
            bv[i] = *(const f32x4*)(bptr + k0 + i * 4);
        }
        __syncthreads();   // all waves done reading previous tile

        // convert fp32 -> bf16 hi/lo, write LDS (2x ds_write_b128 per tile)
        ushort8 h, l;
#pragma unroll
        for (int half = 0; half < 2; ++half) {
#pragma unroll
            for (int i = 0; i < 8; ++i) {
                float v = av[half * 2 + (i >> 2)][i & 3];
                unsigned short hh = f2bf_rne(v);
                h[i] = hh;
                l[i] = f2bf_rne(v - bf2f(hh));
            }
            *(ushort8*)&Ah[srow][shalf * 16 + half * 8] = h;
            *(ushort8*)&Al[srow][shalf * 16 + half * 8] = l;
        }
#pragma unroll
        for (int half = 0; half < 2; ++half) {
#pragma unroll
            for (int i = 0; i < 8; ++i) {
                float v = bv[half * 2 + (i >> 2)][i & 3];
                unsigned short hh = f2bf_rne(v);
                h[i] = hh;
                l[i] = f2bf_rne(v - bf2f(hh));
            }
            *(ushort8*)&Bh[srow][shalf * 16 + half * 8] = h;
            *(ushort8*)&Bl[srow][shalf * 16 + half * 8] = l;
        }
        __syncthreads();   // tile visible

        // fragment loads: A row = lane&15 (+16*f), k = (lane>>4)*8 .. +7
        bf16x8 afh[4], afl[4], bfh[4], bfl[4];
#pragma unroll
        for (int f = 0; f < 4; ++f) {
            const int ar = wr * 64 + f * 16 + l15;
            afh[f] = *(const bf16x8*)&Ah[ar][kg * 8];
            afl[f] = *(const bf16x8*)&Al[ar][kg * 8];
            const int br = wc * 64 + f * 16 + l15;
            bfh[f] = *(const bf16x8*)&Bh[br][kg * 8];
            bfl[f] = *(const bf16x8*)&Bl[br][kg * 8];
        }
#pragma unroll
        for (int fm = 0; fm < 4; ++fm)
#pragma unroll
            for (int fn = 0; fn < 4; ++fn) {
                acc[fm][fn] = __builtin_amdgcn_mfma_f32_16x16x32_bf16(
                    afh[fm], bfh[fn], acc[fm][fn], 0, 0, 0);
                acc[fm][fn] = __builtin_amdgcn_mfma_f32_16x16x32_bf16(
                    afh[fm], bfl[fn], acc[fm][fn], 0, 0, 0);
                acc[fm][fn] = __builtin_amdgcn_mfma_f32_16x16x32_bf16(
                    afl[fm], bfh[fn], acc[fm][fn], 0, 0, 0);
            }
    }

    // epilogue: C/D layout col = lane&15, row = (lane>>4)*4 + reg  [m89/m91]
#pragma unroll
    for (int fm = 0; fm < 4; ++fm)
#pragma unroll
        for (int fn = 0; fn < 4; ++fn) {
            const int col = n0 + wc * 64 + fn * 16 + l15;
            const float bvv = bias ? bias[col] : 0.f;
#pragma unroll
            for (int j = 0; j < 4; ++j) {
                const int row = m0 + wr * 64 + fm * 16 + kg * 4 + j;
                if (row < M) C[(size_t)row * N + col] = acc[fm][fn][j] + bvv;
            }
        }
}

// ---------------------------------------------------------------------------
// Task gather: per batch b — selector cross-attention pooling over patches.
// ---------------------------------------------------------------------------
__global__ __launch_bounds__(256)
void task_gather_kernel(const float* __restrict__ x, const float* __restrict__ tokens,
                        float* __restrict__ task_x, float* __restrict__ out_tok)
{
    const int b = blockIdx.x;
    const int tid = threadIdx.x;
    __shared__ float sel[8][772];   // padded: bank-spread across s
    __shared__ float g[8][200];

    for (int l = tid; l < 8 * 192; l += 256) {
        int s = l / 192, c4 = l % 192;
        float4 v = *(const float4*)&tokens[((size_t)b * 9 + 1 + s) * 768 + c4 * 4];
        sel[s][c4 * 4 + 0] = v.x; sel[s][c4 * 4 + 1] = v.y;
        sel[s][c4 * 4 + 2] = v.z; sel[s][c4 * 4 + 3] = v.w;
        *(float4*)&out_tok[((size_t)b * 9 + 1 + s) * 768 + c4 * 4] = v;
    }
    __syncthreads();

    const float token_scale = 0.03608439182435161f;  // 768^-0.5
    for (int idx = tid; idx < 197 * 8; idx += 256) {
        int n = idx >> 3, s = idx & 7;
        const float* xr = &x[((size_t)b * 197 + n) * 768];
        float acc = 0.f;
        for (int c4 = 0; c4 < 192; ++c4) {
            float4 xv = *(const float4*)&xr[c4 * 4];
            acc = fmaf(xv.x, sel[s][c4 * 4 + 0], acc);
            acc = fmaf(xv.y, sel[s][c4 * 4 + 1], acc);
            acc = fmaf(xv.z, sel[s][c4 * 4 + 2], acc);
            acc = fmaf(xv.w, sel[s][c4 * 4 + 3], acc);
        }
        g[s][n] = acc * token_scale;
    }
    __syncthreads();

    const int w = tid >> 6, lane = tid & 63;
    for (int s = w; s < 8; s += 4) {
        float vals[4];
        float m = -1e30f;
#pragma unroll
        for (int t = 0; t < 4; ++t) {
            int n = lane + 64 * t;
            vals[t] = (n < 197) ? g[s][n] : -1e30f;
            m = fmaxf(m, vals[t]);
        }
#pragma unroll
        for (int off = 32; off >= 1; off >>= 1) m = fmaxf(m, __shfl_xor(m, off, 64));
        float sum = 0.f;
#pragma unroll
        for (int t = 0; t < 4; ++t) {
            int n = lane + 64 * t;
            if (n < 197) { vals[t] = __expf(vals[t] - m); sum += vals[t]; }
        }
#pragma unroll
        for (int off = 32; off >= 1; off >>= 1) sum += __shfl_xor(sum, off, 64);
        float inv = 1.f / sum;
#pragma unroll
        for (int t = 0; t < 4; ++t) {
            int n = lane + 64 * t;
            if (n < 197) g[s][n] = vals[t] * inv;
        }
    }
    __syncthreads();

    if (tid < 192) {
        float4 acc8[8];
#pragma unroll
        for (int s = 0; s < 8; ++s) acc8[s] = make_float4(0.f, 0.f, 0.f, 0.f);
        for (int n = 0; n < 197; ++n) {
            float4 xv = *(const float4*)&x[((size_t)b * 197 + n) * 768 + tid * 4];
#pragma unroll
            for (int s = 0; s < 8; ++s) {
                float gw = g[s][n];
                acc8[s].x = fmaf(gw, xv.x, acc8[s].x);
                acc8[s].y = fmaf(gw, xv.y, acc8[s].y);
                acc8[s].z = fmaf(gw, xv.z, acc8[s].z);
                acc8[s].w = fmaf(gw, xv.w, acc8[s].w);
            }
        }
#pragma unroll
        for (int s = 0; s < 8; ++s)
            *(float4*)&task_x[((size_t)b * 9 + 1 + s) * 768 + tid * 4] = acc8[s];
        float4 cls = *(const float4*)&tokens[((size_t)b * 9) * 768 + tid * 4];
        *(float4*)&task_x[((size_t)b * 9) * 768 + tid * 4] = cls;
    }
}

// ---------------------------------------------------------------------------
// Main attention via MFMA (hi/lo bf16 split), per (h, b) block, 4 waves.
// S^T = K@Q^T, softmax in-register, out^T = V^T @ P^T.
// [VALIDATED r7: attn path passed, absmax 9.8e-4]
// ---------------------------------------------------------------------------
__global__ __launch_bounds__(256)
void attn_mfma_kernel(const float* __restrict__ qkv2, float* __restrict__ attn_o)
{
    __shared__ alignas(16) unsigned short Khi[198][64], Klo[198][64];
    __shared__ alignas(16) unsigned short Vthi[64][232], Vtlo[64][232];
    __shared__ alignas(16) unsigned short Phi[4][16][208], Plo[4][16][208];

    const int h = blockIdx.x, b = blockIdx.y;
    const int tid = threadIdx.x;
    const int wave = tid >> 6, lane = tid & 63;
    const int l15 = lane & 15, kg = lane >> 4;

    const size_t base = (size_t)b * 197 * 2304 + (size_t)h * 64;

    // ---- stage K (hi/lo, swizzled) and V^T (hi/lo) ----
    for (int l = tid; l < 197 * 16; l += 256) {
        int n = l >> 4, d4 = l & 15;
        const float* p = &qkv2[base + (size_t)n * 2304 + d4 * 4];
        float4 k4 = *(const float4*)(p + 768);
        float4 v4 = *(const float4*)(p + 1536);
        float kf[4] = {k4.x, k4.y, k4.z, k4.w};
        float vf[4] = {v4.x, v4.y, v4.z, v4.w};
        // K row n, dims d4*4..+3 -> swizzled 16B slot ((d4>>1) ^ (n&7))
        const int off = (((d4 >> 1) ^ (n & 7)) << 3) + ((d4 & 1) << 2);
        ushort4v kh, kl;
#pragma unroll
        for (int i = 0; i < 4; ++i) {
            unsigned short hh = f2bf_rne(kf[i]);
            kh[i] = hh;
            kl[i] = f2bf_rne(kf[i] - bf2f(hh));
        }
        *(ushort4v*)&Khi[n][off] = kh;
        *(ushort4v*)&Klo[n][off] = kl;
#pragma unroll
        for (int i = 0; i < 4; ++i) {
            unsigned short hh = f2bf_rne(vf[i]);
            Vthi[d4 * 4 + i][n] = hh;
            Vtlo[d4 * 4 + i][n] = f2bf_rne(vf[i] - bf2f(hh));
        }
    }
    // zero Vt key-columns 197..207 (read by PV step 6 with p==0; avoid 0*NaN)
    for (int l = tid; l < 64 * 11; l += 256) {
        int d = l / 11, c = 197 + l % 11;
        Vthi[d][c] = 0;
        Vtlo[d][c] = 0;
    }
    __syncthreads();

    // ---- per-wave query tiles (16 queries each; 13 tiles) ----
    for (int qt = wave; qt < 13; qt += 4) {
        const int n0 = qt * 16;
        const int qrow = (n0 + l15 < 197) ? (n0 + l15) : 196;

        // Q B-frags from global, pre-scaled by hd^-0.5 = 0.125 (exact)
        bf16x8 qh[2], ql[2];
#pragma unroll
        for (int s = 0; s < 2; ++s) {
            const float* qp = &qkv2[base + (size_t)qrow * 2304 + kg * 8 + 32 * s];
            float4 qa = *(const float4*)qp;
            float4 qb = *(const float4*)(qp + 4);
            float qf[8] = {qa.x, qa.y, qa.z, qa.w, qb.x, qb.y, qb.z, qb.w};
#pragma unroll
            for (int i = 0; i < 8; ++i) {
                float v = qf[i] * 0.125f;
                unsigned short hh = f2bf_rne(v);
                qh[s][i] = (short)hh;
                ql[s][i] = (short)f2bf_rne(v - bf2f(hh));
            }
        }

        // S^T = K @ Q^T : 13 key-tiles x 2 K-steps x 3 (hi/lo) MFMA
        f32x4 st[13];
#pragma unroll
        for (int t = 0; t < 13; ++t) st[t] = (f32x4){0.f, 0.f, 0.f, 0.f};
#pragma unroll
        for (int t = 0; t < 13; ++t) {
            const int r = 16 * t + l15;               // key row held by this lane
            const bool ok = (t < 12) || (l15 < 5);    // rows 197+ -> zero frag
#pragma unroll
            for (int s = 0; s < 2; ++s) {
                bf16x8 kh = {0, 0, 0, 0, 0, 0, 0, 0};
                bf16x8 kl = {0, 0, 0, 0, 0, 0, 0, 0};
                if (ok) {
                    const int off = (((kg + 4 * s) ^ (l15 & 7)) << 3);
                    kh = *(const bf16x8*)&Khi[r][off];
                    kl = *(const bf16x8*)&Klo[r][off];
                }
                st[t] = __builtin_amdgcn_mfma_f32_16x16x32_bf16(kh, qh[s], st[t], 0, 0, 0);
                st[t] = __builtin_amdgcn_mfma_f32_16x16x32_bf16(kh, ql[s], st[t], 0, 0, 0);
                st[t] = __builtin_amdgcn_mfma_f32_16x16x32_bf16(kl, qh[s], st[t], 0, 0, 0);
            }
        }

        // softmax over keys for query col l15 (rows = keys 16t+kg*4+j)
        float m = -1e30f;
#pragma unroll
        for (int t = 0; t < 13; ++t)
#pragma unroll
            for (int j = 0; j < 4; ++j) {
                const int key = 16 * t + kg * 4 + j;
                float v = (key < 197) ? st[t][j] : -1e30f;
                st[t][j] = v;
                m = fmaxf(m, v);
            }
        m = fmaxf(m, __shfl_xor(m, 16, 64));
        m = fmaxf(m, __shfl_xor(m, 32, 64));
        float sum = 0.f;
#pragma unroll
        for (int t = 0; t < 13; ++t)
#pragma unroll
            for (int j = 0; j < 4; ++j) {
                float e = __expf(st[t][j] - m);   // masked -> exp(-huge) = 0
                st[t][j] = e;
                sum += e;
            }
        sum += __shfl_xor(sum, 16, 64);
        sum += __shfl_xor(sum, 32, 64);
        const float inv = 1.f / sum;              // applied at epilogue

        // pack P (unnormalized) to per-wave LDS, bf16 hi/lo
#pragma unroll
        for (int t = 0; t < 13; ++t) {
            ushort4v ph, pl;
#pragma unroll
            for (int j = 0; j < 4; ++j) {
                unsigned short hh = f2bf_rne(st[t][j]);
                ph[j] = hh;
                pl[j] = f2bf_rne(st[t][j] - bf2f(hh));
            }
            *(ushort4v*)&Phi[wave][l15][16 * t + kg * 4] = ph;
            *(ushort4v*)&Plo[wave][l15][16 * t + kg * 4] = pl;
        }

        // out^T = V^T @ P^T : 7 K-steps (32 keys) x 4 d-frags x 3 MFMA
        f32x4 ao[4];
#pragma unroll
        for (int fd = 0; fd < 4; ++fd) ao[fd] = (f32x4){0.f, 0.f, 0.f, 0.f};
#pragma unroll
        for (int s = 0; s < 7; ++s) {
            const bool act = (s < 6) || (kg < 2);   // keys 208+ -> zero frags
            bf16x8 ph = {0, 0, 0, 0, 0, 0, 0, 0};
            bf16x8 pl = {0, 0, 0, 0, 0, 0, 0, 0};
            if (act) {
                ph = *(const bf16x8*)&Phi[wave][l15][kg * 8 + 32 * s];
                pl = *(const bf16x8*)&Plo[wave][l15][kg * 8 + 32 * s];
            }
#pragma unroll
            for (int fd = 0; fd < 4; ++fd) {
                bf16x8 vh = {0, 0, 0, 0, 0, 0, 0, 0};
                bf16x8 vl = {0, 0, 0, 0, 0, 0, 0, 0};
                if (act) {
                    vh = *(const bf16x8*)&Vthi[fd * 16 + l15][kg * 8 + 32 * s];
                    vl = *(const bf16x8*)&Vtlo[fd * 16 + l15][kg * 8 + 32 * s];
                }
                ao[fd] = __builtin_amdgcn_mfma_f32_16x16x32_bf16(vh, ph, ao[fd], 0, 0, 0);
                ao[fd] = __builtin_amdgcn_mfma_f32_16x16x32_bf16(vh, pl, ao[fd], 0, 0, 0);
                ao[fd] = __builtin_amdgcn_mfma_f32_16x16x32_bf16(vl, ph, ao[fd], 0, 0, 0);
            }
        }

        // epilogue: out[query n0+l15][d = fd*16 + kg*4 + j] = ao * inv
        if (n0 + l15 < 197) {
            float* op = &attn_o[((size_t)(b * 197 + n0 + l15)) * 768 + h * 64];
#pragma unroll
            for (int fd = 0; fd < 4; ++fd) {
                float4 o = make_float4(ao[fd][0] * inv, ao[fd][1] * inv,
                                       ao[fd][2] * inv, ao[fd][3] * inv);
                *(float4*)(op + fd * 16 + kg * 4) = o;
            }
        }
    }
}

// ---------------------------------------------------------------------------
// Task attention v2, per (h, b) block, 64 threads (1 wave).
// Uses precomputed task_qkv = task_x @ qkv_w.T (from gemm_mfma).
// 17 keys = 8 prompt K + 9 task K; only the cls-row query matters.
// Coalesced loads, butterfly-reduce dots, in-register softmax. No LDS.
// ---------------------------------------------------------------------------
__global__ __launch_bounds__(64)
void task_attn2_kernel(const float* __restrict__ task_qkv, const float* __restrict__ prompts,
                       float* __restrict__ out0)
{
    const int h = blockIdx.x, b = blockIdx.y;
    const int d = threadIdx.x;   // 0..63

    const float q0 = task_qkv[((size_t)b * 9) * 2304 + h * 64 + d] * 0.125f;

    float s[17];
#pragma unroll
    for (int j = 0; j < 17; ++j) {
        float kv = (j < 8)
            ? prompts[(size_t)(j * 12 + h) * 64 + d]                             // prompt keys (i=0,nt=0)
            : task_qkv[((size_t)b * 9 + (j - 8)) * 2304 + 768 + h * 64 + d];     // task K rows
        float prod = q0 * kv;
#pragma unroll
        for (int off = 32; off >= 1; off >>= 1) prod += __shfl_xor(prod, off, 64);
        s[j] = prod;   // broadcast on all lanes after butterfly
    }
    float m = s[0];
#pragma unroll
    for (int j = 1; j < 17; ++j) m = fmaxf(m, s[j]);
    float sum = 0.f;
#pragma unroll
    for (int j = 0; j < 17; ++j) { s[j] = __expf(s[j] - m); sum += s[j]; }
    float acc = 0.f;
#pragma unroll
    for (int j = 0; j < 17; ++j) {
        float vv = (j < 8)
            ? prompts[(size_t)61440 + (size_t)(j * 12 + h) * 64 + d]             // prompt values (i=1,nt=0)
            : task_qkv[((size_t)b * 9 + (j - 8)) * 2304 + 1536 + h * 64 + d];    // task V rows
        acc = fmaf(s[j], vv, acc);
    }
    out0[((size_t)b * 12 + h) * 64 + d] = acc / sum;
}

// ---------------------------------------------------------------------------
// Task projection of the cls row only -> tokens_out[:, :, 0, :]
// ---------------------------------------------------------------------------
__global__ __launch_bounds__(256)
void task_proj_kernel(const float* __restrict__ out0, const float* __restrict__ proj_w,
                      const float* __restrict__ proj_b, float* __restrict__ out_tok)
{
    const int b = blockIdx.x;
    const int col = blockIdx.y * 256 + threadIdx.x;
    __shared__ float xr[768];
    for (int l = threadIdx.x; l < 768; l += 256) xr[l] = out0[(size_t)b * 768 + l];
    __syncthreads();
    const float* wp = &proj_w[(size_t)col * 768];
    float acc = proj_b[col];
    for (int c4 = 0; c4 < 192; ++c4) {
        float4 wv = *(const float4*)&wp[c4 * 4];
        acc = fmaf(wv.x, xr[c4 * 4 + 0], acc);
        acc = fmaf(wv.y, xr[c4 * 4 + 1], acc);
        acc = fmaf(wv.z, xr[c4 * 4 + 2], acc);
        acc = fmaf(wv.w, xr[c4 * 4 + 3], acc);
    }
    out_tok[((size_t)b * 9) * 768 + col] = acc;
}

// ---------------------------------------------------------------------------
extern "C" void kernel_launch(void* const* d_in, const int* in_sizes, int n_in,
                              void* d_out, int out_size, void* d_ws, size_t ws_size,
                              hipStream_t stream)
{
    const float* x       = (const float*)d_in[0];
    const float* tokens  = (const float*)d_in[1];
    const float* qkv_w   = (const float*)d_in[2];
    const float* proj_w  = (const float*)d_in[3];
    const float* proj_b  = (const float*)d_in[4];
    const float* prompts = (const float*)d_in[5];

    float* xo      = (float*)d_out;                 // 12608*768
    float* out_tok = xo + (size_t)12608 * 768;      // 64*9*768

    float* qkv2     = (float*)d_ws;                        // 12608*2304
    float* attn_o   = qkv2 + (size_t)12608 * 2304;         // 12608*768
    float* task_x   = attn_o + (size_t)12608 * 768;        // 64*9*768
    float* out0     = task_x + (size_t)64 * 9 * 768;       // 64*768
    float* task_qkv = out0 + (size_t)64 * 768;             // 576*2304

    task_gather_kernel<<<dim3(64), 256, 0, stream>>>(x, tokens, task_x, out_tok);

    gemm_mfma_kernel<<<dim3(2304 / 128, (12608 + 127) / 128), 256, 0, stream>>>(
        x, qkv_w, nullptr, qkv2, 12608, 2304, 768);

    attn_mfma_kernel<<<dim3(12, 64), 256, 0, stream>>>(qkv2, attn_o);

    gemm_mfma_kernel<<<dim3(768 / 128, (12608 + 127) / 128), 256, 0, stream>>>(
        attn_o, proj_w, proj_b, xo, 12608, 768, 768);

    // task path: qkv projection of the 576 task rows via MFMA GEMM
    gemm_mfma_kernel<<<dim3(2304 / 128, (576 + 127) / 128), 256, 0, stream>>>(
        task_x, qkv_w, nullptr, task_qkv, 576, 2304, 768);

    task_attn2_kernel<<<dim3(12, 64), 64, 0, stream>>>(task_qkv, prompts, out0);

    task_proj_kernel<<<dim3(64, 3), 256, 0, stream>>>(out0, proj_w, proj_b, out_tok);
}

// Round 10
// 623.663 us; speedup vs baseline: 2.0373x; 1.1203x over previous
//
#include <hip/hip_runtime.h>
#include <hip/hip_bf16.h>
#include <cstddef>
#include <cstdint>

// Problem constants
// x:(64,197,768) tokens:(1,64,9,768) qkv_w:(2304,768) proj_w:(768,768)
// proj_b:(768) prompts:(2,10,8,12,64). NUM_HEADS=12, hd=64, T_TASK=0.

typedef __attribute__((ext_vector_type(8))) short    bf16x8;   // MFMA A/B frag (8 bf16)
typedef __attribute__((ext_vector_type(8))) unsigned short ushort8;
typedef __attribute__((ext_vector_type(4))) unsigned short ushort4v;
typedef __attribute__((ext_vector_type(4))) float    f32x4;    // MFMA C/D frag

__device__ __forceinline__ unsigned short f2bf_rne(float f) {
    unsigned int u = __float_as_uint(f);
    u += 0x7fff + ((u >> 16) & 1);           // round-to-nearest-even
    return (unsigned short)(u >> 16);
}
__device__ __forceinline__ float bf2f(unsigned short h) {
    return __uint_as_float(((unsigned int)h) << 16);
}

// ---------------------------------------------------------------------------
// fp32 -> bf16 hi/lo split, one pass (memory-bound). n4 = n/4.
// ---------------------------------------------------------------------------
__global__ __launch_bounds__(256)
void split_hl_kernel(const float* __restrict__ in, unsigned short* __restrict__ hi,
                     unsigned short* __restrict__ lo, int n4)
{
    int i = blockIdx.x * 256 + threadIdx.x;
    const int stride = gridDim.x * 256;
    for (; i < n4; i += stride) {
        float4 v = ((const float4*)in)[i];
        float f[4] = {v.x, v.y, v.z, v.w};
        ushort4v h4, l4;
#pragma unroll
        for (int j = 0; j < 4; ++j) {
            unsigned short hh = f2bf_rne(f[j]);
            h4[j] = hh;
            l4[j] = f2bf_rne(f[j] - bf2f(hh));
        }
        ((ushort4v*)hi)[i] = h4;
        ((ushort4v*)lo)[i] = l4;
    }
}

// ---------------------------------------------------------------------------
// Pre-split bf16 hi/lo MFMA GEMM: C(M,N) = A(M,K) @ Bw(N,K)^T (+bias).
// Operands arrive as separate hi/lo bf16 arrays -> NO conversion in the loop
// (r9 counters: in-loop f2bf was the VALU bottleneck, VALUBusy 39% > MfmaUtil 25%).
// 128x128 tile, 4 waves, 64x64/wave, BK=32, reg->LDS staging (ushort8),
// unpadded [128][32] tiles: ds patterns land 8 lanes per 4-bank group = min cycles.
// N % 128 == 0, K % 32 == 0; A-rows clamped to M-1 (epilogue guards row<M).
// ---------------------------------------------------------------------------
__global__ __launch_bounds__(256)
void gemm_hl_kernel(const unsigned short* __restrict__ Ah_g, const unsigned short* __restrict__ Al_g,
                    const unsigned short* __restrict__ Bh_g, const unsigned short* __restrict__ Bl_g,
                    const float* __restrict__ bias, float* __restrict__ C,
                    int M, int N, int K)
{
    __shared__ alignas(16) unsigned short As_h[128][32], As_l[128][32];
    __shared__ alignas(16) unsigned short Bs_h[128][32], Bs_l[128][32];

    const int tid = threadIdx.x;
    const int m0 = blockIdx.y * 128;
    const int n0 = blockIdx.x * 128;
    const int wave = tid >> 6, lane = tid & 63;
    const int wr = wave >> 1, wc = wave & 1;      // 2x2 wave grid
    const int l15 = lane & 15, kg = lane >> 4;    // frag row/col + k-group

    f32x4 acc[4][4];
#pragma unroll
    for (int i = 0; i < 4; ++i)
#pragma unroll
        for (int j = 0; j < 4; ++j) acc[i][j] = (f32x4){0.f, 0.f, 0.f, 0.f};

    // staging: wave w owns one tile {A-hi, A-lo, B-hi, B-lo};
    // chunk c = 16 rows; lane covers (row = c*16 + lane>>2, 16B quarter = lane&3)
    const unsigned short* srcbase =
        (wave == 0) ? Ah_g : (wave == 1) ? Al_g : (wave == 2) ? Bh_g : Bl_g;
    unsigned short* ldsbase =
        (wave == 0) ? &As_h[0][0] : (wave == 1) ? &As_l[0][0]
                                  : (wave == 2) ? &Bs_h[0][0] : &Bs_l[0][0];
    const bool isA = (wave < 2);
    const int rbase = isA ? m0 : n0;
    const int rmax  = isA ? (M - 1) : (N - 1);

    const unsigned short* sp[8];
#pragma unroll
    for (int c = 0; c < 8; ++c) {
        int r = rbase + c * 16 + (lane >> 2);
        if (r > rmax) r = rmax;                    // clamp: real data, no NaN
        sp[c] = srcbase + (size_t)r * K + (lane & 3) * 8;
    }
    const int loff = (lane >> 2) * 32 + (lane & 3) * 8;   // lane's slot within a chunk

    for (int k0 = 0; k0 < K; k0 += 32) {
        // issue global loads first: latency overlaps the barrier wait
        ushort8 stg[8];
#pragma unroll
        for (int c = 0; c < 8; ++c) {
            stg[c] = *(const ushort8*)sp[c];
            sp[c] += 32;
        }
        __syncthreads();   // all waves done reading previous tile
#pragma unroll
        for (int c = 0; c < 8; ++c)
            *(ushort8*)(ldsbase + c * 512 + loff) = stg[c];
        __syncthreads();   // tile visible

        bf16x8 afh[4], afl[4], bfh[4], bfl[4];
#pragma unroll
        for (int f = 0; f < 4; ++f) {
            const int ar = wr * 64 + f * 16 + l15;
            afh[f] = *(const bf16x8*)&As_h[ar][kg * 8];
            afl[f] = *(const bf16x8*)&As_l[ar][kg * 8];
            const int br = wc * 64 + f * 16 + l15;
            bfh[f] = *(const bf16x8*)&Bs_h[br][kg * 8];
            bfl[f] = *(const bf16x8*)&Bs_l[br][kg * 8];
        }
#pragma unroll
        for (int fm = 0; fm < 4; ++fm)
#pragma unroll
            for (int fn = 0; fn < 4; ++fn) {
                acc[fm][fn] = __builtin_amdgcn_mfma_f32_16x16x32_bf16(
                    afh[fm], bfh[fn], acc[fm][fn], 0, 0, 0);
                acc[fm][fn] = __builtin_amdgcn_mfma_f32_16x16x32_bf16(
                    afh[fm], bfl[fn], acc[fm][fn], 0, 0, 0);
                acc[fm][fn] = __builtin_amdgcn_mfma_f32_16x16x32_bf16(
                    afl[fm], bfh[fn], acc[fm][fn], 0, 0, 0);
            }
    }

    // epilogue: C/D layout col = lane&15, row = (lane>>4)*4 + reg  [validated r3/r7]
#pragma unroll
    for (int fm = 0; fm < 4; ++fm)
#pragma unroll
        for (int fn = 0; fn < 4; ++fn) {
            const int col = n0 + wc * 64 + fn * 16 + l15;
            const float bvv = bias ? bias[col] : 0.f;
#pragma unroll
            for (int j = 0; j < 4; ++j) {
                const int row = m0 + wr * 64 + fm * 16 + kg * 4 + j;
                if (row < M) C[(size_t)row * N + col] = acc[fm][fn][j] + bvv;
            }
        }
}

// ---------------------------------------------------------------------------
// Task gather: selector softmax-pooling; writes task_x as bf16 hi/lo + out_tok.
// ---------------------------------------------------------------------------
__global__ __launch_bounds__(256)
void task_gather_kernel(const float* __restrict__ x, const float* __restrict__ tokens,
                        unsigned short* __restrict__ tx_hi, unsigned short* __restrict__ tx_lo,
                        float* __restrict__ out_tok)
{
    const int b = blockIdx.x;
    const int tid = threadIdx.x;
    __shared__ float sel[8][772];
    __shared__ float g[8][200];

    for (int l = tid; l < 8 * 192; l += 256) {
        int s = l / 192, c4 = l % 192;
        float4 v = *(const float4*)&tokens[((size_t)b * 9 + 1 + s) * 768 + c4 * 4];
        sel[s][c4 * 4 + 0] = v.x; sel[s][c4 * 4 + 1] = v.y;
        sel[s][c4 * 4 + 2] = v.z; sel[s][c4 * 4 + 3] = v.w;
        *(float4*)&out_tok[((size_t)b * 9 + 1 + s) * 768 + c4 * 4] = v;
    }
    __syncthreads();

    const float token_scale = 0.03608439182435161f;  // 768^-0.5
    for (int idx = tid; idx < 197 * 8; idx += 256) {
        int n = idx >> 3, s = idx & 7;
        const float* xr = &x[((size_t)b * 197 + n) * 768];
        float acc = 0.f;
        for (int c4 = 0; c4 < 192; ++c4) {
            float4 xv = *(const float4*)&xr[c4 * 4];
            acc = fmaf(xv.x, sel[s][c4 * 4 + 0], acc);
            acc = fmaf(xv.y, sel[s][c4 * 4 + 1], acc);
            acc = fmaf(xv.z, sel[s][c4 * 4 + 2], acc);
            acc = fmaf(xv.w, sel[s][c4 * 4 + 3], acc);
        }
        g[s][n] = acc * token_scale;
    }
    __syncthreads();

    const int w = tid >> 6, lane = tid & 63;
    for (int s = w; s < 8; s += 4) {
        float vals[4];
        float m = -1e30f;
#pragma unroll
        for (int t = 0; t < 4; ++t) {
            int n = lane + 64 * t;
            vals[t] = (n < 197) ? g[s][n] : -1e30f;
            m = fmaxf(m, vals[t]);
        }
#pragma unroll
        for (int off = 32; off >= 1; off >>= 1) m = fmaxf(m, __shfl_xor(m, off, 64));
        float sum = 0.f;
#pragma unroll
        for (int t = 0; t < 4; ++t) {
            int n = lane + 64 * t;
            if (n < 197) { vals[t] = __expf(vals[t] - m); sum += vals[t]; }
        }
#pragma unroll
        for (int off = 32; off >= 1; off >>= 1) sum += __shfl_xor(sum, off, 64);
        float inv = 1.f / sum;
#pragma unroll
        for (int t = 0; t < 4; ++t) {
            int n = lane + 64 * t;
            if (n < 197) g[s][n] = vals[t] * inv;
        }
    }
    __syncthreads();

    if (tid < 192) {
        float4 acc8[8];
#pragma unroll
        for (int s = 0; s < 8; ++s) acc8[s] = make_float4(0.f, 0.f, 0.f, 0.f);
        for (int n = 0; n < 197; ++n) {
            float4 xv = *(const float4*)&x[((size_t)b * 197 + n) * 768 + tid * 4];
#pragma unroll
            for (int s = 0; s < 8; ++s) {
                float gw = g[s][n];
                acc8[s].x = fmaf(gw, xv.x, acc8[s].x);
                acc8[s].y = fmaf(gw, xv.y, acc8[s].y);
                acc8[s].z = fmaf(gw, xv.z, acc8[s].z);
                acc8[s].w = fmaf(gw, xv.w, acc8[s].w);
            }
        }
#pragma unroll
        for (int s = 0; s < 8; ++s) {
            float f[4] = {acc8[s].x, acc8[s].y, acc8[s].z, acc8[s].w};
            ushort4v h4, l4;
#pragma unroll
            for (int j = 0; j < 4; ++j) {
                unsigned short hh = f2bf_rne(f[j]);
                h4[j] = hh;
                l4[j] = f2bf_rne(f[j] - bf2f(hh));
            }
            *(ushort4v*)&tx_hi[((size_t)b * 9 + 1 + s) * 768 + tid * 4] = h4;
            *(ushort4v*)&tx_lo[((size_t)b * 9 + 1 + s) * 768 + tid * 4] = l4;
        }
        float4 cls = *(const float4*)&tokens[((size_t)b * 9) * 768 + tid * 4];
        float cf[4] = {cls.x, cls.y, cls.z, cls.w};
        ushort4v h4, l4;
#pragma unroll
        for (int j = 0; j < 4; ++j) {
            unsigned short hh = f2bf_rne(cf[j]);
            h4[j] = hh;
            l4[j] = f2bf_rne(cf[j] - bf2f(hh));
        }
        *(ushort4v*)&tx_hi[((size_t)b * 9) * 768 + tid * 4] = h4;
        *(ushort4v*)&tx_lo[((size_t)b * 9) * 768 + tid * 4] = l4;
    }
}

// ---------------------------------------------------------------------------
// Main attention via MFMA (hi/lo bf16 split), per (h, b) block, 4 waves.
// S^T = K@Q^T, softmax in-register, out^T = V^T @ P^T.
// Output written directly as bf16 hi/lo (feeds proj GEMM, no re-conversion).
// [core VALIDATED r7: passed, absmax 9.8e-4]
// ---------------------------------------------------------------------------
__global__ __launch_bounds__(256)
void attn_mfma_kernel(const float* __restrict__ qkv2,
                      unsigned short* __restrict__ ao_hi, unsigned short* __restrict__ ao_lo)
{
    __shared__ alignas(16) unsigned short Khi[198][64], Klo[198][64];
    __shared__ alignas(16) unsigned short Vthi[64][232], Vtlo[64][232];
    __shared__ alignas(16) unsigned short Phi[4][16][208], Plo[4][16][208];

    const int h = blockIdx.x, b = blockIdx.y;
    const int tid = threadIdx.x;
    const int wave = tid >> 6, lane = tid & 63;
    const int l15 = lane & 15, kg = lane >> 4;

    const size_t base = (size_t)b * 197 * 2304 + (size_t)h * 64;

    // ---- stage K (hi/lo, swizzled) and V^T (hi/lo) ----
    for (int l = tid; l < 197 * 16; l += 256) {
        int n = l >> 4, d4 = l & 15;
        const float* p = &qkv2[base + (size_t)n * 2304 + d4 * 4];
        float4 k4 = *(const float4*)(p + 768);
        float4 v4 = *(const float4*)(p + 1536);
        float kf[4] = {k4.x, k4.y, k4.z, k4.w};
        float vf[4] = {v4.x, v4.y, v4.z, v4.w};
        const int off = (((d4 >> 1) ^ (n & 7)) << 3) + ((d4 & 1) << 2);
        ushort4v kh, kl;
#pragma unroll
        for (int i = 0; i < 4; ++i) {
            unsigned short hh = f2bf_rne(kf[i]);
            kh[i] = hh;
            kl[i] = f2bf_rne(kf[i] - bf2f(hh));
        }
        *(ushort4v*)&Khi[n][off] = kh;
        *(ushort4v*)&Klo[n][off] = kl;
#pragma unroll
        for (int i = 0; i < 4; ++i) {
            unsigned short hh = f2bf_rne(vf[i]);
            Vthi[d4 * 4 + i][n] = hh;
            Vtlo[d4 * 4 + i][n] = f2bf_rne(vf[i] - bf2f(hh));
        }
    }
    for (int l = tid; l < 64 * 11; l += 256) {
        int d = l / 11, c = 197 + l % 11;
        Vthi[d][c] = 0;
        Vtlo[d][c] = 0;
    }
    __syncthreads();

    for (int qt = wave; qt < 13; qt += 4) {
        const int n0 = qt * 16;
        const int qrow = (n0 + l15 < 197) ? (n0 + l15) : 196;

        bf16x8 qh[2], ql[2];
#pragma unroll
        for (int s = 0; s < 2; ++s) {
            const float* qp = &qkv2[base + (size_t)qrow * 2304 + kg * 8 + 32 * s];
            float4 qa = *(const float4*)qp;
            float4 qb = *(const float4*)(qp + 4);
            float qf[8] = {qa.x, qa.y, qa.z, qa.w, qb.x, qb.y, qb.z, qb.w};
#pragma unroll
            for (int i = 0; i < 8; ++i) {
                float v = qf[i] * 0.125f;
                unsigned short hh = f2bf_rne(v);
                qh[s][i] = (short)hh;
                ql[s][i] = (short)f2bf_rne(v - bf2f(hh));
            }
        }

        f32x4 st[13];
#pragma unroll
        for (int t = 0; t < 13; ++t) st[t] = (f32x4){0.f, 0.f, 0.f, 0.f};
#pragma unroll
        for (int t = 0; t < 13; ++t) {
            const int r = 16 * t + l15;
            const bool ok = (t < 12) || (l15 < 5);
#pragma unroll
            for (int s = 0; s < 2; ++s) {
                bf16x8 kh = {0, 0, 0, 0, 0, 0, 0, 0};
                bf16x8 kl = {0, 0, 0, 0, 0, 0, 0, 0};
                if (ok) {
                    const int off = (((kg + 4 * s) ^ (l15 & 7)) << 3);
                    kh = *(const bf16x8*)&Khi[r][off];
                    kl = *(const bf16x8*)&Klo[r][off];
                }
                st[t] = __builtin_amdgcn_mfma_f32_16x16x32_bf16(kh, qh[s], st[t], 0, 0, 0);
                st[t] = __builtin_amdgcn_mfma_f32_16x16x32_bf16(kh, ql[s], st[t], 0, 0, 0);
                st[t] = __builtin_amdgcn_mfma_f32_16x16x32_bf16(kl, qh[s], st[t], 0, 0, 0);
            }
        }

        float m = -1e30f;
#pragma unroll
        for (int t = 0; t < 13; ++t)
#pragma unroll
            for (int j = 0; j < 4; ++j) {
                const int key = 16 * t + kg * 4 + j;
                float v = (key < 197) ? st[t][j] : -1e30f;
                st[t][j] = v;
                m = fmaxf(m, v);
            }
        m = fmaxf(m, __shfl_xor(m, 16, 64));
        m = fmaxf(m, __shfl_xor(m, 32, 64));
        float sum = 0.f;
#pragma unroll
        for (int t = 0; t < 13; ++t)
#pragma unroll
            for (int j = 0; j < 4; ++j) {
                float e = __expf(st[t][j] - m);
                st[t][j] = e;
                sum += e;
            }
        sum += __shfl_xor(sum, 16, 64);
        sum += __shfl_xor(sum, 32, 64);
        const float inv = 1.f / sum;

#pragma unroll
        for (int t = 0; t < 13; ++t) {
            ushort4v ph, pl;
#pragma unroll
            for (int j = 0; j < 4; ++j) {
                unsigned short hh = f2bf_rne(st[t][j]);
                ph[j] = hh;
                pl[j] = f2bf_rne(st[t][j] - bf2f(hh));
            }
            *(ushort4v*)&Phi[wave][l15][16 * t + kg * 4] = ph;
            *(ushort4v*)&Plo[wave][l15][16 * t + kg * 4] = pl;
        }

        f32x4 ao[4];
#pragma unroll
        for (int fd = 0; fd < 4; ++fd) ao[fd] = (f32x4){0.f, 0.f, 0.f, 0.f};
#pragma unroll
        for (int s = 0; s < 7; ++s) {
            const bool act = (s < 6) || (kg < 2);
            bf16x8 ph = {0, 0, 0, 0, 0, 0, 0, 0};
            bf16x8 pl = {0, 0, 0, 0, 0, 0, 0, 0};
            if (act) {
                ph = *(const bf16x8*)&Phi[wave][l15][kg * 8 + 32 * s];
                pl = *(const bf16x8*)&Plo[wave][l15][kg * 8 + 32 * s];
            }
#pragma unroll
            for (int fd = 0; fd < 4; ++fd) {
                bf16x8 vh = {0, 0, 0, 0, 0, 0, 0, 0};
                bf16x8 vl = {0, 0, 0, 0, 0, 0, 0, 0};
                if (act) {
                    vh = *(const bf16x8*)&Vthi[fd * 16 + l15][kg * 8 + 32 * s];
                    vl = *(const bf16x8*)&Vtlo[fd * 16 + l15][kg * 8 + 32 * s];
                }
                ao[fd] = __builtin_amdgcn_mfma_f32_16x16x32_bf16(vh, ph, ao[fd], 0, 0, 0);
                ao[fd] = __builtin_amdgcn_mfma_f32_16x16x32_bf16(vh, pl, ao[fd], 0, 0, 0);
                ao[fd] = __builtin_amdgcn_mfma_f32_16x16x32_bf16(vl, ph, ao[fd], 0, 0, 0);
            }
        }

        // epilogue: write bf16 hi/lo directly (consumed by proj GEMM)
        if (n0 + l15 < 197) {
            const size_t ob = ((size_t)(b * 197 + n0 + l15)) * 768 + h * 64;
#pragma unroll
            for (int fd = 0; fd < 4; ++fd) {
                ushort4v h4, l4;
#pragma unroll
                for (int j = 0; j < 4; ++j) {
                    float v = ao[fd][j] * inv;
                    unsigned short hh = f2bf_rne(v);
                    h4[j] = hh;
                    l4[j] = f2bf_rne(v - bf2f(hh));
                }
                *(ushort4v*)&ao_hi[ob + fd * 16 + kg * 4] = h4;
                *(ushort4v*)&ao_lo[ob + fd * 16 + kg * 4] = l4;
            }
        }
    }
}

// ---------------------------------------------------------------------------
// Task attention v2 [VALIDATED r9], per (h, b), 1 wave. 17 keys = 8 prompt + 9 task.
// ---------------------------------------------------------------------------
__global__ __launch_bounds__(64)
void task_attn2_kernel(const float* __restrict__ task_qkv, const float* __restrict__ prompts,
                       float* __restrict__ out0)
{
    const int h = blockIdx.x, b = blockIdx.y;
    const int d = threadIdx.x;

    const float q0 = task_qkv[((size_t)b * 9) * 2304 + h * 64 + d] * 0.125f;

    float s[17];
#pragma unroll
    for (int j = 0; j < 17; ++j) {
        float kv = (j < 8)
            ? prompts[(size_t)(j * 12 + h) * 64 + d]
            : task_qkv[((size_t)b * 9 + (j - 8)) * 2304 + 768 + h * 64 + d];
        float prod = q0 * kv;
#pragma unroll
        for (int off = 32; off >= 1; off >>= 1) prod += __shfl_xor(prod, off, 64);
        s[j] = prod;
    }
    float m = s[0];
#pragma unroll
    for (int j = 1; j < 17; ++j) m = fmaxf(m, s[j]);
    float sum = 0.f;
#pragma unroll
    for (int j = 0; j < 17; ++j) { s[j] = __expf(s[j] - m); sum += s[j]; }
    float acc = 0.f;
#pragma unroll
    for (int j = 0; j < 17; ++j) {
        float vv = (j < 8)
            ? prompts[(size_t)61440 + (size_t)(j * 12 + h) * 64 + d]
            : task_qkv[((size_t)b * 9 + (j - 8)) * 2304 + 1536 + h * 64 + d];
        acc = fmaf(s[j], vv, acc);
    }
    out0[((size_t)b * 12 + h) * 64 + d] = acc / sum;
}

// ---------------------------------------------------------------------------
// Task projection of the cls row only -> tokens_out[:, :, 0, :]
// ---------------------------------------------------------------------------
__global__ __launch_bounds__(256)
void task_proj_kernel(const float* __restrict__ out0, const float* __restrict__ proj_w,
                      const float* __restrict__ proj_b, float* __restrict__ out_tok)
{
    const int b = blockIdx.x;
    const int col = blockIdx.y * 256 + threadIdx.x;
    __shared__ float xr[768];
    for (int l = threadIdx.x; l < 768; l += 256) xr[l] = out0[(size_t)b * 768 + l];
    __syncthreads();
    const float* wp = &proj_w[(size_t)col * 768];
    float acc = proj_b[col];
    for (int c4 = 0; c4 < 192; ++c4) {
        float4 wv = *(const float4*)&wp[c4 * 4];
        acc = fmaf(wv.x, xr[c4 * 4 + 0], acc);
        acc = fmaf(wv.y, xr[c4 * 4 + 1], acc);
        acc = fmaf(wv.z, xr[c4 * 4 + 2], acc);
        acc = fmaf(wv.w, xr[c4 * 4 + 3], acc);
    }
    out_tok[((size_t)b * 9) * 768 + col] = acc;
}

// ---------------------------------------------------------------------------
extern "C" void kernel_launch(void* const* d_in, const int* in_sizes, int n_in,
                              void* d_out, int out_size, void* d_ws, size_t ws_size,
                              hipStream_t stream)
{
    const float* x       = (const float*)d_in[0];
    const float* tokens  = (const float*)d_in[1];
    const float* qkv_w   = (const float*)d_in[2];
    const float* proj_w  = (const float*)d_in[3];
    const float* proj_b  = (const float*)d_in[4];
    const float* prompts = (const float*)d_in[5];

    float* xo      = (float*)d_out;                 // 12608*768
    float* out_tok = xo + (size_t)12608 * 768;      // 64*9*768

    // workspace layout (ao_hi/lo alias x_hi/lo: x dead after qkv2 GEMM)
    float*          qkv2  = (float*)d_ws;                               // 29,048,832 f
    unsigned short* x_hi  = (unsigned short*)(qkv2 + (size_t)29048832); // 9,682,944 u
    unsigned short* x_lo  = x_hi + (size_t)9682944;                     // 9,682,944 u
    unsigned short* ao_hi = x_hi;                                       // alias
    unsigned short* ao_lo = x_lo;                                       // alias
    unsigned short* w_hi  = x_lo + (size_t)9682944;                     // 1,769,472 u
    unsigned short* w_lo  = w_hi + (size_t)1769472;
    unsigned short* pw_hi = w_lo + (size_t)1769472;                     // 589,824 u
    unsigned short* pw_lo = pw_hi + (size_t)589824;
    unsigned short* tx_hi = pw_lo + (size_t)589824;                     // 442,368 u
    unsigned short* tx_lo = tx_hi + (size_t)442368;
    float* task_qkv = (float*)(tx_lo + (size_t)442368);                 // 1,327,104 f
    float* out0     = task_qkv + (size_t)1327104;                       // 49,152 f

    // one-time hi/lo splits (memory-bound, ~17 us total)
    split_hl_kernel<<<2048, 256, 0, stream>>>(x, x_hi, x_lo, 12608 * 768 / 4);
    split_hl_kernel<<<1728, 256, 0, stream>>>(qkv_w, w_hi, w_lo, 2304 * 768 / 4);
    split_hl_kernel<<<576, 256, 0, stream>>>(proj_w, pw_hi, pw_lo, 768 * 768 / 4);

    task_gather_kernel<<<dim3(64), 256, 0, stream>>>(x, tokens, tx_hi, tx_lo, out_tok);

    gemm_hl_kernel<<<dim3(2304 / 128, (12608 + 127) / 128), 256, 0, stream>>>(
        x_hi, x_lo, w_hi, w_lo, nullptr, qkv2, 12608, 2304, 768);

    attn_mfma_kernel<<<dim3(12, 64), 256, 0, stream>>>(qkv2, ao_hi, ao_lo);

    gemm_hl_kernel<<<dim3(768 / 128, (12608 + 127) / 128), 256, 0, stream>>>(
        ao_hi, ao_lo, pw_hi, pw_lo, proj_b, xo, 12608, 768, 768);

    gemm_hl_kernel<<<dim3(2304 / 128, (576 + 127) / 128), 256, 0, stream>>>(
        tx_hi, tx_lo, w_hi, w_lo, nullptr, task_qkv, 576, 2304, 768);

    task_attn2_kernel<<<dim3(12, 64), 64, 0, stream>>>(task_qkv, prompts, out0);

    task_proj_kernel<<<dim3(64, 3), 256, 0, stream>>>(out0, proj_w, proj_b, out_tok);
}